// Round 1
// baseline (1427.768 us; speedup 1.0000x reference)
//
#include <hip/hip_runtime.h>
#include <hip/hip_bf16.h>
#include <math.h>

#define D_    1024
#define S_    1024
#define T_    2048
#define H_    16
#define HKV_  4
#define DK_   64
#define KV_   256
#define QKVN  1536
#define E_    8
#define HID_  4096

typedef __attribute__((ext_vector_type(8))) short bf16x8;
typedef __attribute__((ext_vector_type(4))) float f32x4;
#define MFMA16(a,b,c) __builtin_amdgcn_mfma_f32_16x16x32_bf16((a),(b),(c),0,0,0)

__device__ inline unsigned short f2bf(float f){
  union { float f; unsigned u; } x; x.f = f;
  unsigned r = x.u + 0x7fffu + ((x.u >> 16) & 1u);
  return (unsigned short)(r >> 16);
}

// ---------------- RMSNorm 1: x -> h (f32) ----------------
__global__ __launch_bounds__(256) void k_rms1(const float* __restrict__ x, const float* __restrict__ w,
                                              float* __restrict__ h){
  int t = blockIdx.x; int tid = threadIdx.x;
  const float* xr = x + (size_t)t * D_;
  __shared__ float red[256];
  float s = 0.f;
  #pragma unroll
  for (int i = 0; i < 4; i++){ float v = xr[tid + 256*i]; s += v*v; }
  red[tid] = s; __syncthreads();
  for (int o = 128; o > 0; o >>= 1){ if (tid < o) red[tid] += red[tid+o]; __syncthreads(); }
  float rs = rsqrtf(red[0] * (1.f/D_) + 1e-6f);
  #pragma unroll
  for (int i = 0; i < 4; i++){ int d = tid + 256*i; h[(size_t)t*D_ + d] = xr[d] * rs * w[d]; }
}

// ---------------- Effective QKV weights: Weff[k][n], n in [0,1536) ----------------
__global__ __launch_bounds__(256) void k_weff(const float* __restrict__ WqT, const float* __restrict__ WkT,
    const float* __restrict__ WvT, const float* __restrict__ qA, const float* __restrict__ qB,
    const float* __restrict__ kA, const float* __restrict__ kB, const float* __restrict__ vA,
    const float* __restrict__ vB, float* __restrict__ Weff){
  int k = blockIdx.x; int tid = threadIdx.x;
  __shared__ float sA[48];
  if (tid < 16) sA[tid] = qA[k*16 + tid];
  else if (tid < 32) sA[tid] = kA[k*16 + (tid-16)];
  else if (tid < 48) sA[tid] = vA[k*16 + (tid-32)];
  __syncthreads();
  #pragma unroll
  for (int i = 0; i < 6; i++){
    int n = tid + 256*i;
    float base, acc = 0.f;
    if (n < 1024){
      base = WqT[(size_t)k*1024 + n];
      #pragma unroll
      for (int r = 0; r < 16; r++) acc += sA[r] * qB[r*1024 + n];
    } else if (n < 1280){
      int m = n - 1024; base = WkT[(size_t)k*256 + m];
      #pragma unroll
      for (int r = 0; r < 16; r++) acc += sA[16+r] * kB[r*256 + m];
    } else {
      int m = n - 1280; base = WvT[(size_t)k*256 + m];
      #pragma unroll
      for (int r = 0; r < 16; r++) acc += sA[32+r] * vB[r*256 + m];
    }
    Weff[(size_t)k*QKVN + n] = base + 2.0f * acc;
  }
}

// ---------------- f32 tiled GEMM: C[M,N] = A[M,K] @ B[K,N]  (EPI1: += R residual) ----------------
template<int EPI>
__global__ __launch_bounds__(256) void k_gemm_f32(const float* __restrict__ A, const float* __restrict__ B,
    const float* __restrict__ R, float* __restrict__ C, int M, int N, int K){
  __shared__ float Ast[16][132];   // [k][m] transposed
  __shared__ float Bs[16][68];     // [k][n]
  int tid = threadIdx.x;
  int tx = tid & 15, ty = tid >> 4;
  int m0 = blockIdx.y * 128, n0 = blockIdx.x * 64;
  float acc[8][4] = {};
  for (int kt = 0; kt < K; kt += 16){
    #pragma unroll
    for (int i = 0; i < 2; i++){
      int r = (tid >> 2) + i*64;
      int kc = (tid & 3) * 4;
      float4 v = *(const float4*)&A[(size_t)(m0 + r)*K + kt + kc];
      Ast[kc+0][r] = v.x; Ast[kc+1][r] = v.y; Ast[kc+2][r] = v.z; Ast[kc+3][r] = v.w;
    }
    {
      int kr = tid >> 4, c = (tid & 15) * 4;
      *(float4*)&Bs[kr][c] = *(const float4*)&B[(size_t)(kt + kr)*N + n0 + c];
    }
    __syncthreads();
    #pragma unroll
    for (int k = 0; k < 16; k++){
      float a[8], b[4];
      *(float4*)&a[0] = *(const float4*)&Ast[k][ty*8];
      *(float4*)&a[4] = *(const float4*)&Ast[k][ty*8+4];
      *(float4*)&b[0] = *(const float4*)&Bs[k][tx*4];
      #pragma unroll
      for (int im = 0; im < 8; im++)
        #pragma unroll
        for (int in = 0; in < 4; in++) acc[im][in] += a[im]*b[in];
    }
    __syncthreads();
  }
  #pragma unroll
  for (int im = 0; im < 8; im++){
    int m = m0 + ty*8 + im;
    float4 v = make_float4(acc[im][0], acc[im][1], acc[im][2], acc[im][3]);
    size_t off = (size_t)m*N + n0 + tx*4;
    if (EPI == 1){
      float4 rr = *(const float4*)&R[off];
      v.x += rr.x; v.y += rr.y; v.z += rr.z; v.w += rr.w;
    }
    *(float4*)&C[off] = v;
  }
}

// ---------------- RoPE + layout split ----------------
__global__ __launch_bounds__(256) void k_rope(const float* __restrict__ QKV, const float* __restrict__ fc,
    const float* __restrict__ fs, float* __restrict__ Qr, float* __restrict__ Kr, float* __restrict__ Vr){
  int t = blockIdx.x; int tid = threadIdx.x;
  int b = t >> 10, s = t & 1023;
  const float* row = QKV + (size_t)t * QKVN;
  #pragma unroll
  for (int i = 0; i < 6; i++){
    int idx = tid + 256*i;
    int hh = idx >> 6, d = idx & 63;
    float v = row[idx];
    if (hh < 20){  // Q or K: apply rope
      float c = fc[s*64 + d], sn = fs[s*64 + d];
      float partner = row[hh*64 + ((d < 32) ? d + 32 : d - 32)];
      float o = v * c + ((d < 32) ? -partner : partner) * sn;
      if (hh < 16) Qr[(((size_t)(b*16 + hh))*S_ + s)*64 + d] = o;
      else         Kr[(((size_t)(b*4 + (hh-16)))*S_ + s)*64 + d] = o;
    } else {
      Vr[(((size_t)(b*4 + (hh-20)))*S_ + s)*64 + d] = v;
    }
  }
}

// ---------------- causal GQA attention (flash-style, f32) ----------------
__global__ __launch_bounds__(256) void k_attn(const float* __restrict__ Qr, const float* __restrict__ Kr,
    const float* __restrict__ Vr, float* __restrict__ ctx){
  int qb = blockIdx.x;          // 0..63 (16-query tiles)
  int bh = blockIdx.y;          // 0..31
  int b = bh >> 4, h = bh & 15, kh = h >> 2;
  const float* Qb = Qr + (((size_t)(b*16 + h))*S_ + qb*16)*64;
  const float* Kb = Kr + ((size_t)(b*4 + kh))*S_*64;
  const float* Vb = Vr + ((size_t)(b*4 + kh))*S_*64;
  __shared__ float Kl[64*65];
  __shared__ float Vl[64*65];
  __shared__ float qt[64*20];   // [d][qi]
  __shared__ float pt[64*20];   // [j][qi]
  int tid = threadIdx.x, l = tid & 63, w = tid >> 6;
  #pragma unroll
  for (int i = 0; i < 4; i++){
    int e2 = tid + 256*i; int qi = e2 >> 6, d = e2 & 63;
    qt[d*20 + qi] = Qb[qi*64 + d] * 0.125f;     // fold DK^-0.5
  }
  __syncthreads();
  float m[4] = {-1e30f,-1e30f,-1e30f,-1e30f};
  float lden[4] = {0,0,0,0};
  float o[4] = {0,0,0,0};
  int q0 = qb*16 + w*4;
  int nch = ((qb*16 + 15) >> 6) + 1;
  for (int c = 0; c < nch; c++){
    #pragma unroll
    for (int i = 0; i < 4; i++){
      int e2 = tid + 256*i; int r = e2 >> 4, cc = (e2 & 15)*4;
      float4 k4 = *(const float4*)&Kb[(size_t)(c*64 + r)*64 + cc];
      float4 v4 = *(const float4*)&Vb[(size_t)(c*64 + r)*64 + cc];
      Kl[r*65+cc] = k4.x; Kl[r*65+cc+1] = k4.y; Kl[r*65+cc+2] = k4.z; Kl[r*65+cc+3] = k4.w;
      Vl[r*65+cc] = v4.x; Vl[r*65+cc+1] = v4.y; Vl[r*65+cc+2] = v4.z; Vl[r*65+cc+3] = v4.w;
    }
    __syncthreads();
    int key = c*64 + l;
    float s0=0,s1=0,s2=0,s3=0;
    #pragma unroll 8
    for (int d = 0; d < 64; d++){
      float kv = Kl[l*65 + d];
      float4 qv = *(const float4*)&qt[d*20 + w*4];
      s0 += kv*qv.x; s1 += kv*qv.y; s2 += kv*qv.z; s3 += kv*qv.w;
    }
    if (key > q0+0) s0 = -1e30f;
    if (key > q0+1) s1 = -1e30f;
    if (key > q0+2) s2 = -1e30f;
    if (key > q0+3) s3 = -1e30f;
    float sv[4] = {s0,s1,s2,s3};
    #pragma unroll
    for (int i = 0; i < 4; i++){
      float M = sv[i];
      for (int msk = 32; msk; msk >>= 1) M = fmaxf(M, __shfl_xor(M, msk));
      float nm = fmaxf(m[i], M);
      float al = __expf(m[i] - nm);
      float p = __expf(sv[i] - nm);
      float P = p;
      for (int msk = 32; msk; msk >>= 1) P += __shfl_xor(P, msk);
      lden[i] = lden[i]*al + P;
      o[i] *= al;
      m[i] = nm;
      pt[l*20 + w*4 + i] = p;
    }
    #pragma unroll 8
    for (int j = 0; j < 64; j++){
      float4 pv = *(const float4*)&pt[j*20 + w*4];
      float vv = Vl[j*65 + l];
      o[0] += pv.x*vv; o[1] += pv.y*vv; o[2] += pv.z*vv; o[3] += pv.w*vv;
    }
    __syncthreads();
  }
  int t0 = b*S_ + qb*16 + w*4;
  #pragma unroll
  for (int i = 0; i < 4; i++)
    ctx[(size_t)(t0 + i)*D_ + h*64 + l] = o[i] / lden[i];
}

// ---------------- RMSNorm2 + task_emb -> xf (f32) + xf_bf ----------------
__global__ __launch_bounds__(256) void k_rms2(const float* __restrict__ x1, const float* __restrict__ w,
    const float* __restrict__ temb, const int* __restrict__ task_id,
    float* __restrict__ xf, unsigned short* __restrict__ xf_bf){
  int t = blockIdx.x; int tid = threadIdx.x;
  const float* xr = x1 + (size_t)t * D_;
  __shared__ float red[256];
  float s = 0.f;
  #pragma unroll
  for (int i = 0; i < 4; i++){ float v = xr[tid + 256*i]; s += v*v; }
  red[tid] = s; __syncthreads();
  for (int o = 128; o > 0; o >>= 1){ if (tid < o) red[tid] += red[tid+o]; __syncthreads(); }
  float rs = rsqrtf(red[0] * (1.f/D_) + 1e-6f);
  int tk = task_id[t];
  #pragma unroll
  for (int i = 0; i < 4; i++){
    int d = tid + 256*i;
    float v = xr[d] * rs * w[d] + temb[(size_t)tk*D_ + d];
    xf[(size_t)t*D_ + d] = v;
    xf_bf[(size_t)t*D_ + d] = f2bf(v);
  }
}

// ---------------- routing ----------------
__global__ void k_zero8(int* cnt){ if (threadIdx.x < 8) cnt[threadIdx.x] = 0; }

__global__ __launch_bounds__(64) void k_gate(const float* __restrict__ xf, const float* __restrict__ gW,
    const float* __restrict__ gA, const float* __restrict__ gB,
    int* __restrict__ top_e, float* __restrict__ top_w, int* __restrict__ cnt){
  int t = blockIdx.x; int l = threadIdx.x;
  const float* xr = xf + (size_t)t * D_;
  float aw[8] = {0,0,0,0,0,0,0,0};
  float aa[16] = {0,0,0,0,0,0,0,0,0,0,0,0,0,0,0,0};
  for (int u = 0; u < 16; u++){
    int d = l + u*64;
    float xv = xr[d];
    const float* gwr = gW + (size_t)d*8;
    #pragma unroll
    for (int e = 0; e < 8; e++) aw[e] += xv * gwr[e];
    const float* gar = gA + (size_t)d*16;
    #pragma unroll
    for (int r = 0; r < 16; r++) aa[r] += xv * gar[r];
  }
  #pragma unroll
  for (int e = 0; e < 8; e++){ float v = aw[e]; for (int msk=32; msk; msk>>=1) v += __shfl_xor(v, msk); aw[e] = v; }
  #pragma unroll
  for (int r = 0; r < 16; r++){ float v = aa[r]; for (int msk=32; msk; msk>>=1) v += __shfl_xor(v, msk); aa[r] = v; }
  if (l == 0){
    float lg[8];
    #pragma unroll
    for (int e = 0; e < 8; e++){
      float acc = 0.f;
      #pragma unroll
      for (int r = 0; r < 16; r++) acc += aa[r] * gB[r*8 + e];
      lg[e] = aw[e] + 2.0f * acc;
    }
    int e1 = 0; float v1 = lg[0];
    for (int e = 1; e < 8; e++) if (lg[e] > v1){ v1 = lg[e]; e1 = e; }
    int es = -1; float v2 = -3e38f;
    for (int e = 0; e < 8; e++) if (e != e1 && lg[e] > v2){ v2 = lg[e]; es = e; }
    float z = expf(v2 - v1);
    top_e[2*t] = e1; top_e[2*t+1] = es;
    top_w[2*t] = 1.f/(1.f + z); top_w[2*t+1] = z/(1.f + z);
    atomicAdd(&cnt[e1], 1); atomicAdd(&cnt[es], 1);
  }
}

__global__ void k_scan(const int* cnt, int* offs, int* cursor){
  if (threadIdx.x == 0){
    int a = 0;
    for (int e = 0; e < 8; e++){ offs[e] = a; cursor[e] = a; a += cnt[e]; }
  }
}

__global__ __launch_bounds__(256) void k_build(const int* __restrict__ top_e, const float* __restrict__ top_w,
    int* cursor, int* __restrict__ rowmap, float* __restrict__ roww, int* __restrict__ tok2row){
  int t = blockIdx.x*256 + threadIdx.x;
  #pragma unroll
  for (int s = 0; s < 2; s++){
    int e = top_e[2*t + s];
    int pos = atomicAdd(&cursor[e], 1);
    rowmap[pos] = t; roww[pos] = top_w[2*t + s]; tok2row[2*t + s] = pos;
  }
}

// ---------------- MoE GEMM1: h1[row, 4096] = gather(xf_bf) @ W1[e] + b1 (bf16 out) ----------------
__global__ __launch_bounds__(256) void k_moe1(const unsigned short* __restrict__ xf_bf,
    const float* __restrict__ W1, const float* __restrict__ b1,
    const int* __restrict__ rowmap, const int* __restrict__ cnt, const int* __restrict__ offs,
    unsigned short* __restrict__ h1){
  int e = blockIdx.z;
  int Ne = cnt[e];
  int y0 = blockIdx.y * 64;
  if (y0 >= Ne) return;
  int n0 = blockIdx.x * 64;
  int off = offs[e];
  const float* B = W1 + (size_t)e * D_ * HID_;
  __shared__ unsigned short As[64*72];
  __shared__ unsigned short Bs[64*72];
  int tid = threadIdx.x;
  int l = tid & 63, w = tid >> 6, wr = w >> 1, wc = w & 1;
  f32x4 zz = {0.f,0.f,0.f,0.f};
  f32x4 acc[2][2] = {{zz,zz},{zz,zz}};
  int ac = (tid & 7) * 8;
  int arow[2];
  #pragma unroll
  for (int i = 0; i < 2; i++){
    int r = (tid >> 3) + i*32;
    arow[i] = (y0 + r < Ne) ? rowmap[off + y0 + r] : -1;
  }
  for (int kt = 0; kt < D_; kt += 64){
    #pragma unroll
    for (int i = 0; i < 2; i++){
      int r = (tid >> 3) + i*32;
      uint4 v = make_uint4(0,0,0,0);
      if (arow[i] >= 0) v = *(const uint4*)(xf_bf + (size_t)arow[i]*D_ + kt + ac);
      *(uint4*)(As + r*72 + ac) = v;
    }
    #pragma unroll
    for (int i = 0; i < 4; i++){
      int k = (tid >> 4) + i*16;
      int c = (tid & 15) * 4;
      float4 bv = *(const float4*)&B[(size_t)(kt + k)*HID_ + n0 + c];
      Bs[(c+0)*72 + k] = f2bf(bv.x); Bs[(c+1)*72 + k] = f2bf(bv.y);
      Bs[(c+2)*72 + k] = f2bf(bv.z); Bs[(c+3)*72 + k] = f2bf(bv.w);
    }
    __syncthreads();
    #pragma unroll
    for (int kk = 0; kk < 2; kk++){
      int ko = kk*32 + (l >> 4)*8;
      bf16x8 a0 = *(bf16x8*)(As + (wr*32 + (l & 15))*72 + ko);
      bf16x8 a1 = *(bf16x8*)(As + (wr*32 + 16 + (l & 15))*72 + ko);
      bf16x8 b0 = *(bf16x8*)(Bs + (wc*32 + (l & 15))*72 + ko);
      bf16x8 b1v = *(bf16x8*)(Bs + (wc*32 + 16 + (l & 15))*72 + ko);
      acc[0][0] = MFMA16(a0, b0, acc[0][0]);
      acc[0][1] = MFMA16(a0, b1v, acc[0][1]);
      acc[1][0] = MFMA16(a1, b0, acc[1][0]);
      acc[1][1] = MFMA16(a1, b1v, acc[1][1]);
    }
    __syncthreads();
  }
  #pragma unroll
  for (int t2 = 0; t2 < 2; t2++)
    #pragma unroll
    for (int u = 0; u < 2; u++)
      #pragma unroll
      for (int r = 0; r < 4; r++){
        int ml = wr*32 + t2*16 + (l >> 4)*4 + r;
        if (y0 + ml < Ne){
          int nl = wc*32 + u*16 + (l & 15);
          float v = acc[t2][u][r] + b1[(size_t)e*HID_ + n0 + nl];
          h1[(size_t)(off + y0 + ml)*HID_ + n0 + nl] = f2bf(v);
        }
      }
}

// ---------------- MoE GEMM2 (dual): contrib[row,1024] = w * silu(h1@Wg+bg) * (h1@Wv+bv) ----------------
__global__ __launch_bounds__(256) void k_moe2(const unsigned short* __restrict__ h1,
    const float* __restrict__ Wg, const float* __restrict__ Wv,
    const float* __restrict__ bg, const float* __restrict__ bvv,
    const int* __restrict__ cnt, const int* __restrict__ offs,
    const float* __restrict__ roww, float* __restrict__ contrib){
  int e = blockIdx.z;
  int Ne = cnt[e];
  int y0 = blockIdx.y * 64;
  if (y0 >= Ne) return;
  int n0 = blockIdx.x * 64;
  int off = offs[e];
  const float* Bg = Wg + (size_t)e * HID_ * D_;
  const float* Bv = Wv + (size_t)e * HID_ * D_;
  __shared__ unsigned short As[64*72];
  __shared__ unsigned short Bgs[64*72];
  __shared__ unsigned short Bvs[64*72];
  int tid = threadIdx.x;
  int l = tid & 63, w = tid >> 6, wr = w >> 1, wc = w & 1;
  f32x4 zz = {0.f,0.f,0.f,0.f};
  f32x4 ag[2][2] = {{zz,zz},{zz,zz}}, av[2][2] = {{zz,zz},{zz,zz}};
  int ac = (tid & 7) * 8;
  int arow[2]; bool aval[2];
  #pragma unroll
  for (int i = 0; i < 2; i++){
    int r = (tid >> 3) + i*32;
    aval[i] = (y0 + r) < Ne;
    arow[i] = off + y0 + r;
  }
  for (int kt = 0; kt < HID_; kt += 64){
    #pragma unroll
    for (int i = 0; i < 2; i++){
      int r = (tid >> 3) + i*32;
      uint4 v = make_uint4(0,0,0,0);
      if (aval[i]) v = *(const uint4*)(h1 + (size_t)arow[i]*HID_ + kt + ac);
      *(uint4*)(As + r*72 + ac) = v;
    }
    #pragma unroll
    for (int i = 0; i < 4; i++){
      int k = (tid >> 4) + i*16;
      int c = (tid & 15) * 4;
      float4 g4 = *(const float4*)&Bg[(size_t)(kt + k)*D_ + n0 + c];
      float4 v4 = *(const float4*)&Bv[(size_t)(kt + k)*D_ + n0 + c];
      Bgs[(c+0)*72 + k] = f2bf(g4.x); Bgs[(c+1)*72 + k] = f2bf(g4.y);
      Bgs[(c+2)*72 + k] = f2bf(g4.z); Bgs[(c+3)*72 + k] = f2bf(g4.w);
      Bvs[(c+0)*72 + k] = f2bf(v4.x); Bvs[(c+1)*72 + k] = f2bf(v4.y);
      Bvs[(c+2)*72 + k] = f2bf(v4.z); Bvs[(c+3)*72 + k] = f2bf(v4.w);
    }
    __syncthreads();
    #pragma unroll
    for (int kk = 0; kk < 2; kk++){
      int ko = kk*32 + (l >> 4)*8;
      bf16x8 a0 = *(bf16x8*)(As + (wr*32 + (l & 15))*72 + ko);
      bf16x8 a1 = *(bf16x8*)(As + (wr*32 + 16 + (l & 15))*72 + ko);
      bf16x8 g0 = *(bf16x8*)(Bgs + (wc*32 + (l & 15))*72 + ko);
      bf16x8 g1 = *(bf16x8*)(Bgs + (wc*32 + 16 + (l & 15))*72 + ko);
      bf16x8 v0 = *(bf16x8*)(Bvs + (wc*32 + (l & 15))*72 + ko);
      bf16x8 v1 = *(bf16x8*)(Bvs + (wc*32 + 16 + (l & 15))*72 + ko);
      ag[0][0] = MFMA16(a0, g0, ag[0][0]); ag[0][1] = MFMA16(a0, g1, ag[0][1]);
      ag[1][0] = MFMA16(a1, g0, ag[1][0]); ag[1][1] = MFMA16(a1, g1, ag[1][1]);
      av[0][0] = MFMA16(a0, v0, av[0][0]); av[0][1] = MFMA16(a0, v1, av[0][1]);
      av[1][0] = MFMA16(a1, v0, av[1][0]); av[1][1] = MFMA16(a1, v1, av[1][1]);
    }
    __syncthreads();
  }
  #pragma unroll
  for (int t2 = 0; t2 < 2; t2++)
    #pragma unroll
    for (int u = 0; u < 2; u++)
      #pragma unroll
      for (int r = 0; r < 4; r++){
        int ml = wr*32 + t2*16 + (l >> 4)*4 + r;
        int lr = y0 + ml;
        if (lr < Ne){
          int nl = wc*32 + u*16 + (l & 15);
          int grow = off + lr;
          float g = ag[t2][u][r] + bg[(size_t)e*D_ + n0 + nl];
          float v = av[t2][u][r] + bvv[(size_t)e*D_ + n0 + nl];
          float sg = 1.f/(1.f + expf(-g));
          contrib[(size_t)grow*D_ + n0 + nl] = roww[grow] * g * sg * v;
        }
      }
}

// ---------------- final: out = x1 + contrib[slot0] + contrib[slot1] ----------------
__global__ __launch_bounds__(256) void k_final(const float* __restrict__ x1, const float* __restrict__ contrib,
    const int* __restrict__ tok2row, float* __restrict__ out){
  int t = blockIdx.x; int i = threadIdx.x;
  int r0 = tok2row[2*t], r1 = tok2row[2*t+1];
  float4 a = *(const float4*)&x1[(size_t)t*D_ + i*4];
  float4 c0 = *(const float4*)&contrib[(size_t)r0*D_ + i*4];
  float4 c1 = *(const float4*)&contrib[(size_t)r1*D_ + i*4];
  a.x += c0.x + c1.x; a.y += c0.y + c1.y; a.z += c0.z + c1.z; a.w += c0.w + c1.w;
  *(float4*)&out[(size_t)t*D_ + i*4] = a;
}

extern "C" void kernel_launch(void* const* d_in, const int* in_sizes, int n_in,
                              void* d_out, int out_size, void* d_ws, size_t ws_size,
                              hipStream_t stream){
  (void)in_sizes; (void)n_in; (void)out_size; (void)ws_size;
  const float* x    = (const float*)d_in[0];
  const float* fc   = (const float*)d_in[1];
  const float* fs   = (const float*)d_in[2];
  const int*   tsk  = (const int*)d_in[3];
  const float* n1w  = (const float*)d_in[4];
  const float* n2w  = (const float*)d_in[5];
  const float* WqT  = (const float*)d_in[6];
  const float* WkT  = (const float*)d_in[7];
  const float* WvT  = (const float*)d_in[8];
  const float* WoT  = (const float*)d_in[9];
  const float* qA   = (const float*)d_in[10]; const float* qB = (const float*)d_in[11];
  const float* kA   = (const float*)d_in[12]; const float* kB = (const float*)d_in[13];
  const float* vA   = (const float*)d_in[14]; const float* vB = (const float*)d_in[15];
  const float* gW   = (const float*)d_in[16]; const float* gA = (const float*)d_in[17];
  const float* gB   = (const float*)d_in[18];
  const float* temb = (const float*)d_in[19];
  const float* eW1  = (const float*)d_in[20]; const float* eb1 = (const float*)d_in[21];
  const float* eWg  = (const float*)d_in[22]; const float* ebg = (const float*)d_in[23];
  const float* eWv  = (const float*)d_in[24]; const float* ebv = (const float*)d_in[25];
  float* out = (float*)d_out;

  char* wsc = (char*)d_ws;
  size_t o = 0;
  auto alloc = [&](size_t bytes)->void*{ void* p = wsc + o; o = (o + bytes + 255) & ~(size_t)255; return p; };
  float* h    = (float*)alloc((size_t)T_*D_*4);
  float* Weff = (float*)alloc((size_t)D_*QKVN*4);
  float* QKV  = (float*)alloc((size_t)T_*QKVN*4);
  float* Qr   = (float*)alloc((size_t)T_*D_*4);
  float* Kr   = (float*)alloc((size_t)T_*KV_*4);
  float* Vr   = (float*)alloc((size_t)T_*KV_*4);
  float* ctx  = (float*)alloc((size_t)T_*D_*4);
  float* x1   = (float*)alloc((size_t)T_*D_*4);
  float* xf   = (float*)alloc((size_t)T_*D_*4);
  unsigned short* xf_bf = (unsigned short*)alloc((size_t)T_*D_*2);
  unsigned short* h1    = (unsigned short*)alloc((size_t)2*T_*HID_*2);
  float* contrib = (float*)alloc((size_t)2*T_*D_*4);
  int*   top_e  = (int*)alloc((size_t)T_*2*4);
  float* top_w  = (float*)alloc((size_t)T_*2*4);
  int*   cnt    = (int*)alloc(64);
  int*   offs   = (int*)alloc(64);
  int*   cursor = (int*)alloc(64);
  int*   rowmap = (int*)alloc((size_t)2*T_*4);
  float* roww   = (float*)alloc((size_t)2*T_*4);
  int*   tok2row= (int*)alloc((size_t)2*T_*4);

  k_rms1<<<T_, 256, 0, stream>>>(x, n1w, h);
  k_weff<<<D_, 256, 0, stream>>>(WqT, WkT, WvT, qA, qB, kA, kB, vA, vB, Weff);
  dim3 g1(QKVN/64, T_/128);
  k_gemm_f32<0><<<g1, 256, 0, stream>>>(h, Weff, nullptr, QKV, T_, QKVN, D_);
  k_rope<<<T_, 256, 0, stream>>>(QKV, fc, fs, Qr, Kr, Vr);
  dim3 ga(64, 32);
  k_attn<<<ga, 256, 0, stream>>>(Qr, Kr, Vr, ctx);
  dim3 g2(D_/64, T_/128);
  k_gemm_f32<1><<<g2, 256, 0, stream>>>(ctx, WoT, x, x1, T_, D_, D_);
  k_zero8<<<1, 64, 0, stream>>>(cnt);
  k_rms2<<<T_, 256, 0, stream>>>(x1, n2w, temb, tsk, xf, xf_bf);
  k_gate<<<T_, 64, 0, stream>>>(xf, gW, gA, gB, top_e, top_w, cnt);
  k_scan<<<1, 64, 0, stream>>>(cnt, offs, cursor);
  k_build<<<T_/256, 256, 0, stream>>>(top_e, top_w, cursor, rowmap, roww, tok2row);
  dim3 gm1(HID_/64, T_/64, E_);
  k_moe1<<<gm1, 256, 0, stream>>>(xf_bf, eW1, eb1, rowmap, cnt, offs, h1);
  dim3 gm2(D_/64, T_/64, E_);
  k_moe2<<<gm2, 256, 0, stream>>>(h1, eWg, eWv, ebg, ebv, cnt, offs, roww, contrib);
  k_final<<<T_, 256, 0, stream>>>(x1, contrib, tok2row, out);
}

// Round 2
// 1186.449 us; speedup vs baseline: 1.2034x; 1.2034x over previous
//
#include <hip/hip_runtime.h>
#include <hip/hip_bf16.h>
#include <math.h>

#define D_    1024
#define S_    1024
#define T_    2048
#define KV_   256
#define QKVN  1536
#define E_    8
#define HID_  4096

typedef unsigned short ushort_t;
typedef __attribute__((ext_vector_type(8))) short bf16x8;
typedef __attribute__((ext_vector_type(4))) float f32x4;
#define MFMA16(a,b,c) __builtin_amdgcn_mfma_f32_16x16x32_bf16((a),(b),(c),0,0,0)

__device__ inline ushort_t f2bf(float f){
  union { float f; unsigned u; } x; x.f = f;
  unsigned r = x.u + 0x7fffu + ((x.u >> 16) & 1u);
  return (ushort_t)(r >> 16);
}
__device__ inline float bf2f(ushort_t h){
  union { unsigned u; float f; } x; x.u = ((unsigned)h) << 16; return x.f;
}
__device__ inline void gl_lds16(const void* g, void* l){
  __builtin_amdgcn_global_load_lds(
      (const __attribute__((address_space(1))) void*)g,
      (__attribute__((address_space(3))) void*)l, 16, 0, 0);
}

// ---------------- init: zero counters + zero page ----------------
__global__ void k_init(int* cnt, ushort_t* zp){
  int t = threadIdx.x;
  ((int*)zp)[t] = 0;           // 1024 B zero page
  if (t < 8) cnt[t] = 0;
}

// ---------------- RMSNorm 1: x -> h_hi/h_lo (bf16 split) ----------------
__global__ __launch_bounds__(256) void k_rms1(const float* __restrict__ x, const float* __restrict__ w,
                                              ushort_t* __restrict__ hh, ushort_t* __restrict__ hl){
  int t = blockIdx.x; int tid = threadIdx.x;
  const float* xr = x + (size_t)t * D_;
  __shared__ float red[256];
  float s = 0.f;
  #pragma unroll
  for (int i = 0; i < 4; i++){ float v = xr[tid + 256*i]; s += v*v; }
  red[tid] = s; __syncthreads();
  for (int o = 128; o > 0; o >>= 1){ if (tid < o) red[tid] += red[tid+o]; __syncthreads(); }
  float rs = rsqrtf(red[0] * (1.f/D_) + 1e-6f);
  #pragma unroll
  for (int i = 0; i < 4; i++){
    int d = tid + 256*i;
    float v = xr[d] * rs * w[d];
    ushort_t hi = f2bf(v);
    hh[(size_t)t*D_ + d] = hi;
    hl[(size_t)t*D_ + d] = f2bf(v - bf2f(hi));
  }
}

// ---------------- Effective QKV weights f32: Weff[k][n] ----------------
__global__ __launch_bounds__(256) void k_weff(const float* __restrict__ WqT, const float* __restrict__ WkT,
    const float* __restrict__ WvT, const float* __restrict__ qA, const float* __restrict__ qB,
    const float* __restrict__ kA, const float* __restrict__ kB, const float* __restrict__ vA,
    const float* __restrict__ vB, float* __restrict__ Weff){
  int k = blockIdx.x; int tid = threadIdx.x;
  __shared__ float sA[48];
  if (tid < 16) sA[tid] = qA[k*16 + tid];
  else if (tid < 32) sA[tid] = kA[k*16 + (tid-16)];
  else if (tid < 48) sA[tid] = vA[k*16 + (tid-32)];
  __syncthreads();
  #pragma unroll
  for (int i = 0; i < 6; i++){
    int n = tid + 256*i;
    float base, acc = 0.f;
    if (n < 1024){
      base = WqT[(size_t)k*1024 + n];
      #pragma unroll
      for (int r = 0; r < 16; r++) acc += sA[r] * qB[r*1024 + n];
    } else if (n < 1280){
      int m = n - 1024; base = WkT[(size_t)k*256 + m];
      #pragma unroll
      for (int r = 0; r < 16; r++) acc += sA[16+r] * kB[r*256 + m];
    } else {
      int m = n - 1280; base = WvT[(size_t)k*256 + m];
      #pragma unroll
      for (int r = 0; r < 16; r++) acc += sA[32+r] * vB[r*256 + m];
    }
    Weff[(size_t)k*QKVN + n] = base + 2.0f * acc;
  }
}

// ---------------- transpose + bf16 convert (optionally split hi/lo) ----------------
// in: f32 [K][N] (batch z), out: bf16 [N][K]
template<int SPLIT>
__global__ __launch_bounds__(256) void k_trans(const float* __restrict__ in, ushort_t* __restrict__ oh,
    ushort_t* __restrict__ ol, int K, int N, size_t ibs, size_t obs){
  __shared__ float Lf[64][65];
  int z = blockIdx.z;
  int n0 = blockIdx.x*64, k0 = blockIdx.y*64;
  int t = threadIdx.x;
  {
    int r = t >> 2, c0 = (t & 3) * 16;
    const float* src = in + (size_t)z*ibs + (size_t)(k0 + r)*N + n0 + c0;
    #pragma unroll
    for (int i = 0; i < 4; i++){
      float4 v = *(const float4*)(src + i*4);
      int c = c0 + i*4;
      Lf[r][c] = v.x; Lf[r][c+1] = v.y; Lf[r][c+2] = v.z; Lf[r][c+3] = v.w;
    }
  }
  __syncthreads();
  int n = t >> 2, ks = (t & 3) * 16;
  ushort_t hb[16], lb[16];
  #pragma unroll
  for (int i = 0; i < 16; i++){
    float v = Lf[ks + i][n];
    ushort_t hi = f2bf(v);
    hb[i] = hi;
    if (SPLIT) lb[i] = f2bf(v - bf2f(hi));
  }
  size_t o = (size_t)z*obs + (size_t)(n0 + n)*K + k0 + ks;
  *(uint4*)(oh + o) = *(const uint4*)hb;
  *(uint4*)(oh + o + 8) = *(const uint4*)(hb + 8);
  if (SPLIT){
    *(uint4*)(ol + o) = *(const uint4*)lb;
    *(uint4*)(ol + o + 8) = *(const uint4*)(lb + 8);
  }
}

// ---------------- split-bf16 (3-term) MFMA GEMM: C[M,N] = A@B (+R), fp32-accurate ----------------
// A: hi/lo [M][K] bf16; B: hi/lo [N][K] bf16 (pre-transposed). tile 64m x 128n, BK=32.
template<int EPI>
__global__ __launch_bounds__(256) void k_gemm3(const ushort_t* __restrict__ Ahi, const ushort_t* __restrict__ Alo,
    const ushort_t* __restrict__ Bhi, const ushort_t* __restrict__ Blo,
    const float* __restrict__ R, float* __restrict__ C, int M, int N, int K){
  __shared__ ushort_t Ah[64*32], Al[64*32], Bh[128*32], Bl[128*32];
  int tid = threadIdx.x, l = tid & 63, w = tid >> 6;
  int m0 = blockIdx.y*64, n0 = blockIdx.x*128;
  int lr = l >> 2, lc = (l & 3) * 8;
  const ushort_t* pah = Ahi + (size_t)(m0 + 16*w + lr)*K + lc;
  const ushort_t* pal = Alo + (size_t)(m0 + 16*w + lr)*K + lc;
  const ushort_t* pbh[2]; const ushort_t* pbl[2];
  #pragma unroll
  for (int i = 0; i < 2; i++){
    int r = (2*w + i)*16 + lr;
    pbh[i] = Bhi + (size_t)(n0 + r)*K + lc;
    pbl[i] = Blo + (size_t)(n0 + r)*K + lc;
  }
  f32x4 zz = {0.f,0.f,0.f,0.f};
  f32x4 acc[2][4] = {{zz,zz,zz,zz},{zz,zz,zz,zz}};
  int wr = w >> 1, wc = w & 1;
  for (int kt = 0; kt < K; kt += 32){
    gl_lds16(pah + kt, (void*)(Ah + w*512));
    gl_lds16(pal + kt, (void*)(Al + w*512));
    #pragma unroll
    for (int i = 0; i < 2; i++){
      gl_lds16(pbh[i] + kt, (void*)(Bh + (2*w+i)*512));
      gl_lds16(pbl[i] + kt, (void*)(Bl + (2*w+i)*512));
    }
    __syncthreads();
    bf16x8 ah[2], al[2], bh[4], bl[4];
    #pragma unroll
    for (int i = 0; i < 2; i++){
      int off = (wr*32 + i*16 + (l & 15))*32 + (l >> 4)*8;
      ah[i] = *(const bf16x8*)(Ah + off);
      al[i] = *(const bf16x8*)(Al + off);
    }
    #pragma unroll
    for (int j = 0; j < 4; j++){
      int off = (wc*64 + j*16 + (l & 15))*32 + (l >> 4)*8;
      bh[j] = *(const bf16x8*)(Bh + off);
      bl[j] = *(const bf16x8*)(Bl + off);
    }
    #pragma unroll
    for (int i = 0; i < 2; i++)
      #pragma unroll
      for (int j = 0; j < 4; j++){
        acc[i][j] = MFMA16(ah[i], bh[j], acc[i][j]);
        acc[i][j] = MFMA16(ah[i], bl[j], acc[i][j]);
        acc[i][j] = MFMA16(al[i], bh[j], acc[i][j]);
      }
    __syncthreads();
  }
  int row4 = (l >> 4)*4, col = l & 15;
  #pragma unroll
  for (int i = 0; i < 2; i++)
    #pragma unroll
    for (int r = 0; r < 4; r++){
      int m = m0 + wr*32 + i*16 + row4 + r;
      #pragma unroll
      for (int j = 0; j < 4; j++){
        int n = n0 + wc*64 + j*16 + col;
        float v = acc[i][j][r];
        if (EPI == 1) v += R[(size_t)m*N + n];
        C[(size_t)m*N + n] = v;
      }
    }
}

// ---------------- RoPE + layout split ----------------
__global__ __launch_bounds__(256) void k_rope(const float* __restrict__ QKV, const float* __restrict__ fc,
    const float* __restrict__ fs, float* __restrict__ Qr, float* __restrict__ Kr, float* __restrict__ Vr){
  int t = blockIdx.x; int tid = threadIdx.x;
  int b = t >> 10, s = t & 1023;
  const float* row = QKV + (size_t)t * QKVN;
  #pragma unroll
  for (int i = 0; i < 6; i++){
    int idx = tid + 256*i;
    int hh = idx >> 6, d = idx & 63;
    float v = row[idx];
    if (hh < 20){
      float c = fc[s*64 + d], sn = fs[s*64 + d];
      float partner = row[hh*64 + ((d < 32) ? d + 32 : d - 32)];
      float o = v * c + ((d < 32) ? -partner : partner) * sn;
      if (hh < 16) Qr[(((size_t)(b*16 + hh))*S_ + s)*64 + d] = o;
      else         Kr[(((size_t)(b*4 + (hh-16)))*S_ + s)*64 + d] = o;
    } else {
      Vr[(((size_t)(b*4 + (hh-20)))*S_ + s)*64 + d] = v;
    }
  }
}

// ---------------- causal GQA attention (flash-style, f32), split-bf16 output ----------------
__global__ __launch_bounds__(256) void k_attn(const float* __restrict__ Qr, const float* __restrict__ Kr,
    const float* __restrict__ Vr, ushort_t* __restrict__ ctxh, ushort_t* __restrict__ ctxl){
  int qb = blockIdx.x;
  int bh = blockIdx.y;
  int b = bh >> 4, h = bh & 15, kh = h >> 2;
  const float* Qb = Qr + (((size_t)(b*16 + h))*S_ + qb*16)*64;
  const float* Kb = Kr + ((size_t)(b*4 + kh))*S_*64;
  const float* Vb = Vr + ((size_t)(b*4 + kh))*S_*64;
  __shared__ float Kl[64*65];
  __shared__ float Vl[64*65];
  __shared__ float qt[64*20];
  __shared__ float pt[64*20];
  int tid = threadIdx.x, l = tid & 63, w = tid >> 6;
  #pragma unroll
  for (int i = 0; i < 4; i++){
    int e2 = tid + 256*i; int qi = e2 >> 6, d = e2 & 63;
    qt[d*20 + qi] = Qb[qi*64 + d] * 0.125f;
  }
  __syncthreads();
  float m[4] = {-1e30f,-1e30f,-1e30f,-1e30f};
  float lden[4] = {0,0,0,0};
  float o[4] = {0,0,0,0};
  int q0 = qb*16 + w*4;
  int nch = ((qb*16 + 15) >> 6) + 1;
  for (int c = 0; c < nch; c++){
    #pragma unroll
    for (int i = 0; i < 4; i++){
      int e2 = tid + 256*i; int r = e2 >> 4, cc = (e2 & 15)*4;
      float4 k4 = *(const float4*)&Kb[(size_t)(c*64 + r)*64 + cc];
      float4 v4 = *(const float4*)&Vb[(size_t)(c*64 + r)*64 + cc];
      Kl[r*65+cc] = k4.x; Kl[r*65+cc+1] = k4.y; Kl[r*65+cc+2] = k4.z; Kl[r*65+cc+3] = k4.w;
      Vl[r*65+cc] = v4.x; Vl[r*65+cc+1] = v4.y; Vl[r*65+cc+2] = v4.z; Vl[r*65+cc+3] = v4.w;
    }
    __syncthreads();
    int key = c*64 + l;
    float s0=0,s1=0,s2=0,s3=0;
    #pragma unroll 8
    for (int d = 0; d < 64; d++){
      float kv = Kl[l*65 + d];
      float4 qv = *(const float4*)&qt[d*20 + w*4];
      s0 += kv*qv.x; s1 += kv*qv.y; s2 += kv*qv.z; s3 += kv*qv.w;
    }
    if (key > q0+0) s0 = -1e30f;
    if (key > q0+1) s1 = -1e30f;
    if (key > q0+2) s2 = -1e30f;
    if (key > q0+3) s3 = -1e30f;
    float sv[4] = {s0,s1,s2,s3};
    #pragma unroll
    for (int i = 0; i < 4; i++){
      float M = sv[i];
      for (int msk = 32; msk; msk >>= 1) M = fmaxf(M, __shfl_xor(M, msk));
      float nm = fmaxf(m[i], M);
      float al = __expf(m[i] - nm);
      float p = __expf(sv[i] - nm);
      float P = p;
      for (int msk = 32; msk; msk >>= 1) P += __shfl_xor(P, msk);
      lden[i] = lden[i]*al + P;
      o[i] *= al;
      m[i] = nm;
      pt[l*20 + w*4 + i] = p;
    }
    #pragma unroll 8
    for (int j = 0; j < 64; j++){
      float4 pv = *(const float4*)&pt[j*20 + w*4];
      float vv = Vl[j*65 + l];
      o[0] += pv.x*vv; o[1] += pv.y*vv; o[2] += pv.z*vv; o[3] += pv.w*vv;
    }
    __syncthreads();
  }
  int t0 = b*S_ + qb*16 + w*4;
  #pragma unroll
  for (int i = 0; i < 4; i++){
    float val = o[i] / lden[i];
    ushort_t hi = f2bf(val);
    size_t idx = (size_t)(t0 + i)*D_ + h*64 + l;
    ctxh[idx] = hi;
    ctxl[idx] = f2bf(val - bf2f(hi));
  }
}

// ---------------- RMSNorm2 + task_emb -> xf (f32) + xf_bf ----------------
__global__ __launch_bounds__(256) void k_rms2(const float* __restrict__ x1, const float* __restrict__ w,
    const float* __restrict__ temb, const int* __restrict__ task_id,
    float* __restrict__ xf, ushort_t* __restrict__ xf_bf){
  int t = blockIdx.x; int tid = threadIdx.x;
  const float* xr = x1 + (size_t)t * D_;
  __shared__ float red[256];
  float s = 0.f;
  #pragma unroll
  for (int i = 0; i < 4; i++){ float v = xr[tid + 256*i]; s += v*v; }
  red[tid] = s; __syncthreads();
  for (int o = 128; o > 0; o >>= 1){ if (tid < o) red[tid] += red[tid+o]; __syncthreads(); }
  float rs = rsqrtf(red[0] * (1.f/D_) + 1e-6f);
  int tk = task_id[t];
  #pragma unroll
  for (int i = 0; i < 4; i++){
    int d = tid + 256*i;
    float v = xr[d] * rs * w[d] + temb[(size_t)tk*D_ + d];
    xf[(size_t)t*D_ + d] = v;
    xf_bf[(size_t)t*D_ + d] = f2bf(v);
  }
}

// ---------------- routing ----------------
__global__ __launch_bounds__(64) void k_gate(const float* __restrict__ xf, const float* __restrict__ gW,
    const float* __restrict__ gA, const float* __restrict__ gB,
    int* __restrict__ top_e, float* __restrict__ top_w, int* __restrict__ cnt){
  int t = blockIdx.x; int l = threadIdx.x;
  const float* xr = xf + (size_t)t * D_;
  float aw[8] = {0,0,0,0,0,0,0,0};
  float aa[16] = {0,0,0,0,0,0,0,0,0,0,0,0,0,0,0,0};
  for (int u = 0; u < 16; u++){
    int d = l + u*64;
    float xv = xr[d];
    const float* gwr = gW + (size_t)d*8;
    #pragma unroll
    for (int e = 0; e < 8; e++) aw[e] += xv * gwr[e];
    const float* gar = gA + (size_t)d*16;
    #pragma unroll
    for (int r = 0; r < 16; r++) aa[r] += xv * gar[r];
  }
  #pragma unroll
  for (int e = 0; e < 8; e++){ float v = aw[e]; for (int msk=32; msk; msk>>=1) v += __shfl_xor(v, msk); aw[e] = v; }
  #pragma unroll
  for (int r = 0; r < 16; r++){ float v = aa[r]; for (int msk=32; msk; msk>>=1) v += __shfl_xor(v, msk); aa[r] = v; }
  if (l == 0){
    float lg[8];
    #pragma unroll
    for (int e = 0; e < 8; e++){
      float acc = 0.f;
      #pragma unroll
      for (int r = 0; r < 16; r++) acc += aa[r] * gB[r*8 + e];
      lg[e] = aw[e] + 2.0f * acc;
    }
    int e1 = 0; float v1 = lg[0];
    for (int e = 1; e < 8; e++) if (lg[e] > v1){ v1 = lg[e]; e1 = e; }
    int es = -1; float v2 = -3e38f;
    for (int e = 0; e < 8; e++) if (e != e1 && lg[e] > v2){ v2 = lg[e]; es = e; }
    float z = expf(v2 - v1);
    top_e[2*t] = e1; top_e[2*t+1] = es;
    top_w[2*t] = 1.f/(1.f + z); top_w[2*t+1] = z/(1.f + z);
    atomicAdd(&cnt[e1], 1); atomicAdd(&cnt[es], 1);
  }
}

__global__ void k_scan(const int* cnt, int* offs, int* cursor){
  if (threadIdx.x == 0){
    int a = 0;
    for (int e = 0; e < 8; e++){ offs[e] = a; cursor[e] = a; a += cnt[e]; }
  }
}

__global__ __launch_bounds__(256) void k_build(const int* __restrict__ top_e, const float* __restrict__ top_w,
    int* cursor, int* __restrict__ rowmap, float* __restrict__ roww, int* __restrict__ tok2row){
  int t = blockIdx.x*256 + threadIdx.x;
  #pragma unroll
  for (int s = 0; s < 2; s++){
    int e = top_e[2*t + s];
    int pos = atomicAdd(&cursor[e], 1);
    rowmap[pos] = t; roww[pos] = top_w[2*t + s]; tok2row[2*t + s] = pos;
  }
}

// ---------------- MoE GEMM1: h1 = gather(xf_bf) @ W1T^T + b1 (bf16 out). tile 128x128, BK=64 ----------------
__global__ __launch_bounds__(256) void k_moe1(const ushort_t* __restrict__ xf_bf, const ushort_t* __restrict__ W1T,
    const float* __restrict__ b1, const int* __restrict__ rowmap, const int* __restrict__ cnt,
    const int* __restrict__ offs, const ushort_t* __restrict__ zp, ushort_t* __restrict__ h1){
  int e = blockIdx.z;
  int Ne = cnt[e];
  int y0 = blockIdx.y * 128;
  if (y0 >= Ne) return;
  int n0 = blockIdx.x * 128;
  int off = offs[e];
  __shared__ ushort_t As[128*64];
  __shared__ ushort_t Bs[128*64];
  int tid = threadIdx.x, l = tid & 63, w = tid >> 6;
  int wr = w >> 1, wc = w & 1;
  int lr = l >> 3, lc = (l & 7) * 8;
  const ushort_t* BT = W1T + (size_t)e * (4096*1024);
  const ushort_t* aptr[4]; int avk[4];
  const ushort_t* bptr[4];
  #pragma unroll
  for (int i = 0; i < 4; i++){
    int t = w*4 + i;
    int r = t*8 + lr;
    bool v = (y0 + r) < Ne;
    int tok = v ? rowmap[off + y0 + r] : 0;
    aptr[i] = v ? (xf_bf + (size_t)tok*D_ + lc) : (zp + lc);
    avk[i] = v ? 1 : 0;
    bptr[i] = BT + (size_t)(n0 + r)*D_ + lc;
  }
  f32x4 zz = {0.f,0.f,0.f,0.f};
  f32x4 acc[4][4] = {{zz,zz,zz,zz},{zz,zz,zz,zz},{zz,zz,zz,zz},{zz,zz,zz,zz}};
  for (int kt = 0; kt < D_; kt += 64){
    #pragma unroll
    for (int i = 0; i < 4; i++){
      int t = w*4 + i;
      gl_lds16(aptr[i] + (avk[i] ? kt : 0), (void*)(As + t*512));
      gl_lds16(bptr[i] + kt, (void*)(Bs + t*512));
    }
    __syncthreads();
    #pragma unroll
    for (int q = 0; q < 2; q++){
      bf16x8 af[4], bfr[4];
      #pragma unroll
      for (int i = 0; i < 4; i++)
        af[i] = *(const bf16x8*)(As + (wr*64 + i*16 + (l & 15))*64 + q*32 + (l >> 4)*8);
      #pragma unroll
      for (int j = 0; j < 4; j++)
        bfr[j] = *(const bf16x8*)(Bs + (wc*64 + j*16 + (l & 15))*64 + q*32 + (l >> 4)*8);
      #pragma unroll
      for (int i = 0; i < 4; i++)
        #pragma unroll
        for (int j = 0; j < 4; j++)
          acc[i][j] = MFMA16(af[i], bfr[j], acc[i][j]);
    }
    __syncthreads();
  }
  int row4 = (l >> 4)*4, col = l & 15;
  #pragma unroll
  for (int i = 0; i < 4; i++)
    #pragma unroll
    for (int r = 0; r < 4; r++){
      int ml = wr*64 + i*16 + row4 + r;
      if (y0 + ml < Ne){
        size_t grow = off + y0 + ml;
        #pragma unroll
        for (int j = 0; j < 4; j++){
          int nl = n0 + wc*64 + j*16 + col;
          h1[grow*HID_ + nl] = f2bf(acc[i][j][r] + b1[(size_t)e*HID_ + nl]);
        }
      }
    }
}

// ---------------- MoE GEMM2 (dual B): tile 128m x 64n, BK=64 ----------------
__global__ __launch_bounds__(256) void k_moe2(const ushort_t* __restrict__ h1, const ushort_t* __restrict__ WgT,
    const ushort_t* __restrict__ WvT, const float* __restrict__ bg, const float* __restrict__ bvv,
    const int* __restrict__ cnt, const int* __restrict__ offs, const float* __restrict__ roww,
    const ushort_t* __restrict__ zp, float* __restrict__ contrib){
  int e = blockIdx.z;
  int Ne = cnt[e];
  int y0 = blockIdx.y * 128;
  if (y0 >= Ne) return;
  int n0 = blockIdx.x * 64;
  int off = offs[e];
  __shared__ ushort_t As[128*64];
  __shared__ ushort_t Gs[64*64];
  __shared__ ushort_t Vs[64*64];
  int tid = threadIdx.x, l = tid & 63, w = tid >> 6;
  int lr = l >> 3, lc = (l & 7) * 8;
  const ushort_t* GT = WgT + (size_t)e * (1024*4096);
  const ushort_t* VT = WvT + (size_t)e * (1024*4096);
  const ushort_t* aptr[4]; int avk[4];
  #pragma unroll
  for (int i = 0; i < 4; i++){
    int t = w*4 + i;
    int r = t*8 + lr;
    bool v = (y0 + r) < Ne;
    aptr[i] = v ? (h1 + (size_t)(off + y0 + r)*HID_ + lc) : (zp + lc);
    avk[i] = v ? 1 : 0;
  }
  const ushort_t* gptr[2]; const ushort_t* vptr[2];
  #pragma unroll
  for (int i = 0; i < 2; i++){
    int t2 = w*2 + i;
    int r = t2*8 + lr;
    gptr[i] = GT + (size_t)(n0 + r)*HID_ + lc;
    vptr[i] = VT + (size_t)(n0 + r)*HID_ + lc;
  }
  f32x4 zz = {0.f,0.f,0.f,0.f};
  f32x4 ag[2][4] = {{zz,zz,zz,zz},{zz,zz,zz,zz}};
  f32x4 av[2][4] = {{zz,zz,zz,zz},{zz,zz,zz,zz}};
  for (int kt = 0; kt < HID_; kt += 64){
    #pragma unroll
    for (int i = 0; i < 4; i++){
      int t = w*4 + i;
      gl_lds16(aptr[i] + (avk[i] ? kt : 0), (void*)(As + t*512));
    }
    #pragma unroll
    for (int i = 0; i < 2; i++){
      int t2 = w*2 + i;
      gl_lds16(gptr[i] + kt, (void*)(Gs + t2*512));
      gl_lds16(vptr[i] + kt, (void*)(Vs + t2*512));
    }
    __syncthreads();
    #pragma unroll
    for (int q = 0; q < 2; q++){
      bf16x8 af[2], gf[4], vf[4];
      #pragma unroll
      for (int i = 0; i < 2; i++)
        af[i] = *(const bf16x8*)(As + (w*32 + i*16 + (l & 15))*64 + q*32 + (l >> 4)*8);
      #pragma unroll
      for (int j = 0; j < 4; j++){
        gf[j] = *(const bf16x8*)(Gs + (j*16 + (l & 15))*64 + q*32 + (l >> 4)*8);
        vf[j] = *(const bf16x8*)(Vs + (j*16 + (l & 15))*64 + q*32 + (l >> 4)*8);
      }
      #pragma unroll
      for (int i = 0; i < 2; i++)
        #pragma unroll
        for (int j = 0; j < 4; j++){
          ag[i][j] = MFMA16(af[i], gf[j], ag[i][j]);
          av[i][j] = MFMA16(af[i], vf[j], av[i][j]);
        }
    }
    __syncthreads();
  }
  int row4 = (l >> 4)*4, col = l & 15;
  #pragma unroll
  for (int i = 0; i < 2; i++)
    #pragma unroll
    for (int r = 0; r < 4; r++){
      int ml = w*32 + i*16 + row4 + r;
      if (y0 + ml < Ne){
        size_t grow = off + y0 + ml;
        float wgt = roww[grow];
        #pragma unroll
        for (int j = 0; j < 4; j++){
          int nl = n0 + j*16 + col;
          float g = ag[i][j][r] + bg[(size_t)e*D_ + nl];
          float v = av[i][j][r] + bvv[(size_t)e*D_ + nl];
          float sg = 1.f/(1.f + expf(-g));
          contrib[grow*D_ + nl] = wgt * g * sg * v;
        }
      }
    }
}

// ---------------- final ----------------
__global__ __launch_bounds__(256) void k_final(const float* __restrict__ x1, const float* __restrict__ contrib,
    const int* __restrict__ tok2row, float* __restrict__ out){
  int t = blockIdx.x; int i = threadIdx.x;
  int r0 = tok2row[2*t], r1 = tok2row[2*t+1];
  float4 a = *(const float4*)&x1[(size_t)t*D_ + i*4];
  float4 c0 = *(const float4*)&contrib[(size_t)r0*D_ + i*4];
  float4 c1 = *(const float4*)&contrib[(size_t)r1*D_ + i*4];
  a.x += c0.x + c1.x; a.y += c0.y + c1.y; a.z += c0.z + c1.z; a.w += c0.w + c1.w;
  *(float4*)&out[(size_t)t*D_ + i*4] = a;
}

extern "C" void kernel_launch(void* const* d_in, const int* in_sizes, int n_in,
                              void* d_out, int out_size, void* d_ws, size_t ws_size,
                              hipStream_t stream){
  (void)in_sizes; (void)n_in; (void)out_size; (void)ws_size;
  const float* x    = (const float*)d_in[0];
  const float* fc   = (const float*)d_in[1];
  const float* fs   = (const float*)d_in[2];
  const int*   tsk  = (const int*)d_in[3];
  const float* n1w  = (const float*)d_in[4];
  const float* n2w  = (const float*)d_in[5];
  const float* WqT  = (const float*)d_in[6];
  const float* WkT  = (const float*)d_in[7];
  const float* WvTp = (const float*)d_in[8];
  const float* WoT  = (const float*)d_in[9];
  const float* qA   = (const float*)d_in[10]; const float* qB = (const float*)d_in[11];
  const float* kA   = (const float*)d_in[12]; const float* kB = (const float*)d_in[13];
  const float* vA   = (const float*)d_in[14]; const float* vB = (const float*)d_in[15];
  const float* gW   = (const float*)d_in[16]; const float* gA = (const float*)d_in[17];
  const float* gB   = (const float*)d_in[18];
  const float* temb = (const float*)d_in[19];
  const float* eW1  = (const float*)d_in[20]; const float* eb1 = (const float*)d_in[21];
  const float* eWg  = (const float*)d_in[22]; const float* ebg = (const float*)d_in[23];
  const float* eWv  = (const float*)d_in[24]; const float* ebv = (const float*)d_in[25];
  float* out = (float*)d_out;

  char* wsc = (char*)d_ws;
  size_t o = 0;
  auto alloc = [&](size_t bytes)->void*{ void* p = wsc + o; o = (o + bytes + 255) & ~(size_t)255; return p; };
  // ---- persistent ----
  ushort_t* zp     = (ushort_t*)alloc(1024);
  int*   cnt    = (int*)alloc(64);
  int*   offs   = (int*)alloc(64);
  int*   cursor = (int*)alloc(64);
  int*   top_e  = (int*)alloc((size_t)T_*2*4);
  float* top_w  = (float*)alloc((size_t)T_*2*4);
  int*   rowmap = (int*)alloc((size_t)2*T_*4);
  float* roww   = (float*)alloc((size_t)2*T_*4);
  int*   tok2row= (int*)alloc((size_t)2*T_*4);
  float* x1     = (float*)alloc((size_t)T_*D_*4);
  float* xf     = (float*)alloc((size_t)T_*D_*4);
  ushort_t* xf_bf  = (ushort_t*)alloc((size_t)T_*D_*2);
  ushort_t* W1T    = (ushort_t*)alloc((size_t)E_*D_*HID_*2);
  ushort_t* WgTb   = (ushort_t*)alloc((size_t)E_*HID_*D_*2);
  ushort_t* WvTb   = (ushort_t*)alloc((size_t)E_*HID_*D_*2);
  ushort_t* WeTh   = (ushort_t*)alloc((size_t)QKVN*D_*2);
  ushort_t* WeTl   = (ushort_t*)alloc((size_t)QKVN*D_*2);
  ushort_t* WoTh   = (ushort_t*)alloc((size_t)D_*D_*2);
  ushort_t* WoTl   = (ushort_t*)alloc((size_t)D_*D_*2);
  // ---- pooled (phase-1 buffers; later overlaid by h1+contrib) ----
  size_t poolbase = o;
  ushort_t* h_hi = (ushort_t*)alloc((size_t)T_*D_*2);
  ushort_t* h_lo = (ushort_t*)alloc((size_t)T_*D_*2);
  float* Weff = (float*)alloc((size_t)D_*QKVN*4);
  float* QKV  = (float*)alloc((size_t)T_*QKVN*4);
  float* Qr   = (float*)alloc((size_t)T_*D_*4);
  float* Kr   = (float*)alloc((size_t)T_*KV_*4);
  float* Vr   = (float*)alloc((size_t)T_*KV_*4);
  ushort_t* ctxh = (ushort_t*)alloc((size_t)T_*D_*2);
  ushort_t* ctxl = (ushort_t*)alloc((size_t)T_*D_*2);
  float* xfp  = (float*)alloc((size_t)T_*D_*4);   // xf lives in pool; safe: last read (k_gate) precedes contrib writes
  xf = xfp;
  // phase-2 overlay: h1 at poolbase, contrib right after (50.3 MB <= 56.6 MB pool)
  ushort_t* h1      = (ushort_t*)(wsc + poolbase);
  float* contrib = (float*)(wsc + poolbase + (size_t)2*T_*HID_*2);

  k_init<<<1, 256, 0, stream>>>(cnt, zp);
  k_rms1<<<T_, 256, 0, stream>>>(x, n1w, h_hi, h_lo);
  k_weff<<<D_, 256, 0, stream>>>(WqT, WkT, WvTp, qA, qB, kA, kB, vA, vB, Weff);
  k_trans<1><<<dim3(QKVN/64, D_/64, 1), 256, 0, stream>>>(Weff, WeTh, WeTl, D_, QKVN, 0, 0);
  k_trans<1><<<dim3(D_/64, D_/64, 1), 256, 0, stream>>>(WoT, WoTh, WoTl, D_, D_, 0, 0);
  k_trans<0><<<dim3(HID_/64, D_/64, E_), 256, 0, stream>>>(eW1, W1T, nullptr, D_, HID_, (size_t)D_*HID_, (size_t)HID_*D_);
  k_trans<0><<<dim3(D_/64, HID_/64, E_), 256, 0, stream>>>(eWg, WgTb, nullptr, HID_, D_, (size_t)HID_*D_, (size_t)D_*HID_);
  k_trans<0><<<dim3(D_/64, HID_/64, E_), 256, 0, stream>>>(eWv, WvTb, nullptr, HID_, D_, (size_t)HID_*D_, (size_t)D_*HID_);
  k_gemm3<0><<<dim3(QKVN/128, T_/64), 256, 0, stream>>>(h_hi, h_lo, WeTh, WeTl, nullptr, QKV, T_, QKVN, D_);
  k_rope<<<T_, 256, 0, stream>>>(QKV, fc, fs, Qr, Kr, Vr);
  k_attn<<<dim3(64, 32), 256, 0, stream>>>(Qr, Kr, Vr, ctxh, ctxl);
  k_gemm3<1><<<dim3(D_/128, T_/64), 256, 0, stream>>>(ctxh, ctxl, WoTh, WoTl, x, x1, T_, D_, D_);
  k_rms2<<<T_, 256, 0, stream>>>(x1, n2w, temb, tsk, xf, xf_bf);
  k_gate<<<T_, 64, 0, stream>>>(xf, gW, gA, gB, top_e, top_w, cnt);
  k_scan<<<1, 64, 0, stream>>>(cnt, offs, cursor);
  k_build<<<T_/256, 256, 0, stream>>>(top_e, top_w, cursor, rowmap, roww, tok2row);
  k_moe1<<<dim3(HID_/128, 16, E_), 256, 0, stream>>>(xf_bf, W1T, eb1, rowmap, cnt, offs, zp, h1);
  k_moe2<<<dim3(D_/64, 16, E_), 256, 0, stream>>>(h1, WgTb, WvTb, ebg, ebv, cnt, offs, roww, zp, contrib);
  k_final<<<T_, 256, 0, stream>>>(x1, contrib, tok2row, out);
}

// Round 3
// 1019.992 us; speedup vs baseline: 1.3998x; 1.1632x over previous
//
#include <hip/hip_runtime.h>
#include <hip/hip_bf16.h>
#include <math.h>

#define D_    1024
#define S_    1024
#define T_    2048
#define KV_   256
#define QKVN  1536
#define E_    8
#define HID_  4096

typedef unsigned short ushort_t;
typedef __attribute__((ext_vector_type(8))) short bf16x8;
typedef __attribute__((ext_vector_type(4))) float f32x4;
#define MFMA16(a,b,c) __builtin_amdgcn_mfma_f32_16x16x32_bf16((a),(b),(c),0,0,0)

__device__ inline ushort_t f2bf(float f){
  union { float f; unsigned u; } x; x.f = f;
  unsigned r = x.u + 0x7fffu + ((x.u >> 16) & 1u);
  return (ushort_t)(r >> 16);
}
__device__ inline float bf2f(ushort_t h){
  union { unsigned u; float f; } x; x.u = ((unsigned)h) << 16; return x.f;
}
__device__ inline void gl_lds16(const void* g, void* l){
  __builtin_amdgcn_global_load_lds(
      (const __attribute__((address_space(1))) void*)g,
      (__attribute__((address_space(3))) void*)l, 16, 0, 0);
}

// ---------------- init: zero counters + zero page ----------------
__global__ void k_init(int* cnt, ushort_t* zp){
  int t = threadIdx.x;
  ((int*)zp)[t] = 0;
  if (t < 8) cnt[t] = 0;
}

// ---------------- RMSNorm 1: x -> h_hi/h_lo (bf16 split) ----------------
__global__ __launch_bounds__(256) void k_rms1(const float* __restrict__ x, const float* __restrict__ w,
                                              ushort_t* __restrict__ hh, ushort_t* __restrict__ hl){
  int t = blockIdx.x; int tid = threadIdx.x;
  const float* xr = x + (size_t)t * D_;
  __shared__ float red[256];
  float s = 0.f;
  #pragma unroll
  for (int i = 0; i < 4; i++){ float v = xr[tid + 256*i]; s += v*v; }
  red[tid] = s; __syncthreads();
  for (int o = 128; o > 0; o >>= 1){ if (tid < o) red[tid] += red[tid+o]; __syncthreads(); }
  float rs = rsqrtf(red[0] * (1.f/D_) + 1e-6f);
  #pragma unroll
  for (int i = 0; i < 4; i++){
    int d = tid + 256*i;
    float v = xr[d] * rs * w[d];
    ushort_t hi = f2bf(v);
    hh[(size_t)t*D_ + d] = hi;
    hl[(size_t)t*D_ + d] = f2bf(v - bf2f(hi));
  }
}

// ---------------- Effective QKV weights f32: Weff[k][n] ----------------
__global__ __launch_bounds__(256) void k_weff(const float* __restrict__ WqT, const float* __restrict__ WkT,
    const float* __restrict__ WvT, const float* __restrict__ qA, const float* __restrict__ qB,
    const float* __restrict__ kA, const float* __restrict__ kB, const float* __restrict__ vA,
    const float* __restrict__ vB, float* __restrict__ Weff){
  int k = blockIdx.x; int tid = threadIdx.x;
  __shared__ float sA[48];
  if (tid < 16) sA[tid] = qA[k*16 + tid];
  else if (tid < 32) sA[tid] = kA[k*16 + (tid-16)];
  else if (tid < 48) sA[tid] = vA[k*16 + (tid-32)];
  __syncthreads();
  #pragma unroll
  for (int i = 0; i < 6; i++){
    int n = tid + 256*i;
    float base, acc = 0.f;
    if (n < 1024){
      base = WqT[(size_t)k*1024 + n];
      #pragma unroll
      for (int r = 0; r < 16; r++) acc += sA[r] * qB[r*1024 + n];
    } else if (n < 1280){
      int m = n - 1024; base = WkT[(size_t)k*256 + m];
      #pragma unroll
      for (int r = 0; r < 16; r++) acc += sA[16+r] * kB[r*256 + m];
    } else {
      int m = n - 1280; base = WvT[(size_t)k*256 + m];
      #pragma unroll
      for (int r = 0; r < 16; r++) acc += sA[32+r] * vB[r*256 + m];
    }
    Weff[(size_t)k*QKVN + n] = base + 2.0f * acc;
  }
}

// ---------------- transpose + bf16 convert (optionally split hi/lo) ----------------
template<int SPLIT>
__global__ __launch_bounds__(256) void k_trans(const float* __restrict__ in, ushort_t* __restrict__ oh,
    ushort_t* __restrict__ ol, int K, int N, size_t ibs, size_t obs){
  __shared__ float Lf[64][65];
  int z = blockIdx.z;
  int n0 = blockIdx.x*64, k0 = blockIdx.y*64;
  int t = threadIdx.x;
  {
    int r = t >> 2, c0 = (t & 3) * 16;
    const float* src = in + (size_t)z*ibs + (size_t)(k0 + r)*N + n0 + c0;
    #pragma unroll
    for (int i = 0; i < 4; i++){
      float4 v = *(const float4*)(src + i*4);
      int c = c0 + i*4;
      Lf[r][c] = v.x; Lf[r][c+1] = v.y; Lf[r][c+2] = v.z; Lf[r][c+3] = v.w;
    }
  }
  __syncthreads();
  int n = t >> 2, ks = (t & 3) * 16;
  ushort_t hb[16], lb[16];
  #pragma unroll
  for (int i = 0; i < 16; i++){
    float v = Lf[ks + i][n];
    ushort_t hi = f2bf(v);
    hb[i] = hi;
    if (SPLIT) lb[i] = f2bf(v - bf2f(hi));
  }
  size_t o = (size_t)z*obs + (size_t)(n0 + n)*K + k0 + ks;
  *(uint4*)(oh + o) = *(const uint4*)hb;
  *(uint4*)(oh + o + 8) = *(const uint4*)(hb + 8);
  if (SPLIT){
    *(uint4*)(ol + o) = *(const uint4*)lb;
    *(uint4*)(ol + o + 8) = *(const uint4*)(lb + 8);
  }
}

// ---------------- split-bf16 (3-term) MFMA GEMM ----------------
template<int EPI>
__global__ __launch_bounds__(256) void k_gemm3(const ushort_t* __restrict__ Ahi, const ushort_t* __restrict__ Alo,
    const ushort_t* __restrict__ Bhi, const ushort_t* __restrict__ Blo,
    const float* __restrict__ R, float* __restrict__ C, int M, int N, int K){
  __shared__ ushort_t Ah[64*32], Al[64*32], Bh[128*32], Bl[128*32];
  int tid = threadIdx.x, l = tid & 63, w = tid >> 6;
  int m0 = blockIdx.y*64, n0 = blockIdx.x*128;
  int lr = l >> 2, lc = (l & 3) * 8;
  const ushort_t* pah = Ahi + (size_t)(m0 + 16*w + lr)*K + lc;
  const ushort_t* pal = Alo + (size_t)(m0 + 16*w + lr)*K + lc;
  const ushort_t* pbh[2]; const ushort_t* pbl[2];
  #pragma unroll
  for (int i = 0; i < 2; i++){
    int r = (2*w + i)*16 + lr;
    pbh[i] = Bhi + (size_t)(n0 + r)*K + lc;
    pbl[i] = Blo + (size_t)(n0 + r)*K + lc;
  }
  f32x4 zz = {0.f,0.f,0.f,0.f};
  f32x4 acc[2][4] = {{zz,zz,zz,zz},{zz,zz,zz,zz}};
  int wr = w >> 1, wc = w & 1;
  for (int kt = 0; kt < K; kt += 32){
    gl_lds16(pah + kt, (void*)(Ah + w*512));
    gl_lds16(pal + kt, (void*)(Al + w*512));
    #pragma unroll
    for (int i = 0; i < 2; i++){
      gl_lds16(pbh[i] + kt, (void*)(Bh + (2*w+i)*512));
      gl_lds16(pbl[i] + kt, (void*)(Bl + (2*w+i)*512));
    }
    __syncthreads();
    bf16x8 ah[2], al[2], bh[4], bl[4];
    #pragma unroll
    for (int i = 0; i < 2; i++){
      int off = (wr*32 + i*16 + (l & 15))*32 + (l >> 4)*8;
      ah[i] = *(const bf16x8*)(Ah + off);
      al[i] = *(const bf16x8*)(Al + off);
    }
    #pragma unroll
    for (int j = 0; j < 4; j++){
      int off = (wc*64 + j*16 + (l & 15))*32 + (l >> 4)*8;
      bh[j] = *(const bf16x8*)(Bh + off);
      bl[j] = *(const bf16x8*)(Bl + off);
    }
    #pragma unroll
    for (int i = 0; i < 2; i++)
      #pragma unroll
      for (int j = 0; j < 4; j++){
        acc[i][j] = MFMA16(ah[i], bh[j], acc[i][j]);
        acc[i][j] = MFMA16(ah[i], bl[j], acc[i][j]);
        acc[i][j] = MFMA16(al[i], bh[j], acc[i][j]);
      }
    __syncthreads();
  }
  int row4 = (l >> 4)*4, col = l & 15;
  #pragma unroll
  for (int i = 0; i < 2; i++)
    #pragma unroll
    for (int r = 0; r < 4; r++){
      int m = m0 + wr*32 + i*16 + row4 + r;
      #pragma unroll
      for (int j = 0; j < 4; j++){
        int n = n0 + wc*64 + j*16 + col;
        float v = acc[i][j][r];
        if (EPI == 1) v += R[(size_t)m*N + n];
        C[(size_t)m*N + n] = v;
      }
    }
}

// ---------------- RoPE: emit Q (scaled) / K bf16 hi-lo [bh][s][dk], V transposed [bkh][dk][s] ----------------
__global__ __launch_bounds__(256) void k_rope(const float* __restrict__ QKV, const float* __restrict__ fc,
    const float* __restrict__ fs,
    ushort_t* __restrict__ Qsh, ushort_t* __restrict__ Qsl,
    ushort_t* __restrict__ Ksh, ushort_t* __restrict__ Ksl,
    ushort_t* __restrict__ Vth, ushort_t* __restrict__ Vtl){
  int t = blockIdx.x; int tid = threadIdx.x;
  int b = t >> 10, s = t & 1023;
  const float* row = QKV + (size_t)t * QKVN;
  #pragma unroll
  for (int i = 0; i < 6; i++){
    int idx = tid + 256*i;
    int hh = idx >> 6, d = idx & 63;
    float v = row[idx];
    if (hh < 20){
      float c = fc[s*64 + d], sn = fs[s*64 + d];
      float partner = row[hh*64 + ((d < 32) ? d + 32 : d - 32)];
      float o = v * c + ((d < 32) ? -partner : partner) * sn;
      if (hh < 16){
        o *= 0.125f;            // fold DK^-0.5 into Q (exact pow2)
        ushort_t hi = f2bf(o);
        size_t qi = (((size_t)(b*16 + hh))*S_ + s)*64 + d;
        Qsh[qi] = hi; Qsl[qi] = f2bf(o - bf2f(hi));
      } else {
        ushort_t hi = f2bf(o);
        size_t ki = (((size_t)(b*4 + (hh-16)))*S_ + s)*64 + d;
        Ksh[ki] = hi; Ksl[ki] = f2bf(o - bf2f(hi));
      }
    } else {
      ushort_t hi = f2bf(v);
      size_t vi = (((size_t)(b*4 + (hh-20)))*64 + d)*S_ + s;
      Vth[vi] = hi; Vtl[vi] = f2bf(v - bf2f(hi));
    }
  }
}

// ---------------- MFMA flash attention, split-bf16 3-term ----------------
__global__ __launch_bounds__(256) void k_attn(
    const ushort_t* __restrict__ Qsh, const ushort_t* __restrict__ Qsl,
    const ushort_t* __restrict__ Ksh, const ushort_t* __restrict__ Ksl,
    const ushort_t* __restrict__ Vth, const ushort_t* __restrict__ Vtl,
    ushort_t* __restrict__ ctxh, ushort_t* __restrict__ ctxl){
  int qt = blockIdx.x;               // 0..15 (64-query tile)
  int bh = blockIdx.y;               // 0..31
  int b = bh >> 4, h = bh & 15, kh = h >> 2;
  __shared__ ushort_t Ks0[64*64], Ks1[64*64];   // [key][dk] hi/lo
  __shared__ ushort_t Vs0[64*64], Vs1[64*64];   // [dk][key] hi/lo
  __shared__ float Pb[4*16*68];                  // per-wave P transpose buffer
  int tid = threadIdx.x, l = tid & 63, w = tid >> 6;
  int i16 = l & 15, quad = l >> 4;
  // Q fragments (A-layout): lane holds Q[q=i16][dk=quad*8+ks*32+j]
  bf16x8 qh_[2], ql_[2];
  {
    const ushort_t* qb = Qsh + (((size_t)(b*16 + h))*S_ + qt*64 + w*16 + i16)*64;
    const ushort_t* ql2 = Qsl + (((size_t)(b*16 + h))*S_ + qt*64 + w*16 + i16)*64;
    #pragma unroll
    for (int ks = 0; ks < 2; ks++){
      qh_[ks] = *(const bf16x8*)(qb + quad*8 + ks*32);
      ql_[ks] = *(const bf16x8*)(ql2 + quad*8 + ks*32);
    }
  }
  const ushort_t* Kbh = Ksh + (size_t)(b*4 + kh)*S_*64;
  const ushort_t* Kbl = Ksl + (size_t)(b*4 + kh)*S_*64;
  const ushort_t* Vbh = Vth + (size_t)(b*4 + kh)*64*S_;
  const ushort_t* Vbl = Vtl + (size_t)(b*4 + kh)*64*S_;
  int sr = l >> 3, sc = (l & 7) * 8;
  float m_[4] = {-1e30f,-1e30f,-1e30f,-1e30f};
  float ld_[4] = {0.f,0.f,0.f,0.f};
  f32x4 zz = {0.f,0.f,0.f,0.f};
  f32x4 O[4] = {zz,zz,zz,zz};
  float* Pw = Pb + w*1088;
  for (int c = 0; c <= qt; c++){
    // ---- stage K/V chunk (hi/lo) via global_load_lds ----
    #pragma unroll
    for (int i = 0; i < 2; i++){
      int seg = w*2 + i;           // 0..7
      int row = seg*8 + sr;        // 0..63
      size_t kg = ((size_t)(c*64 + row))*64 + sc;
      gl_lds16(Kbh + kg, (void*)(Ks0 + seg*512));
      gl_lds16(Kbl + kg, (void*)(Ks1 + seg*512));
      size_t vg = (size_t)row*S_ + c*64 + sc;
      gl_lds16(Vbh + vg, (void*)(Vs0 + seg*512));
      gl_lds16(Vbl + vg, (void*)(Vs1 + seg*512));
    }
    __syncthreads();
    // ---- S = Q K^T (3-term) ----
    f32x4 sA[4];
    #pragma unroll
    for (int sub = 0; sub < 4; sub++){
      f32x4 s = zz;
      #pragma unroll
      for (int ks = 0; ks < 2; ks++){
        int off = (sub*16 + i16)*64 + quad*8 + ks*32;
        bf16x8 kfh = *(const bf16x8*)(Ks0 + off);
        bf16x8 kfl = *(const bf16x8*)(Ks1 + off);
        s = MFMA16(qh_[ks], kfh, s);
        s = MFMA16(ql_[ks], kfh, s);
        s = MFMA16(qh_[ks], kfl, s);
      }
      sA[sub] = s;
    }
    // ---- causal mask (only diagonal chunk) ----
    if (c == qt){
      #pragma unroll
      for (int sub = 0; sub < 4; sub++){
        int key = c*64 + sub*16 + i16;
        #pragma unroll
        for (int r = 0; r < 4; r++){
          int q = qt*64 + w*16 + quad*4 + r;
          if (key > q) sA[sub][r] = -1e30f;
        }
      }
    }
    // ---- online softmax (rows = quad*4+r, cols across {sub, i16}) ----
    float al[4];
    #pragma unroll
    for (int r = 0; r < 4; r++){
      float rm = fmaxf(fmaxf(sA[0][r], sA[1][r]), fmaxf(sA[2][r], sA[3][r]));
      #pragma unroll
      for (int msk = 1; msk < 16; msk <<= 1) rm = fmaxf(rm, __shfl_xor(rm, msk));
      float nm = fmaxf(m_[r], rm);
      al[r] = __expf(m_[r] - nm);
      m_[r] = nm;
      float rs = 0.f;
      #pragma unroll
      for (int sub = 0; sub < 4; sub++){
        float p = __expf(sA[sub][r] - nm);
        sA[sub][r] = p; rs += p;
      }
      #pragma unroll
      for (int msk = 1; msk < 16; msk <<= 1) rs += __shfl_xor(rs, msk);
      ld_[r] = ld_[r]*al[r] + rs;
    }
    #pragma unroll
    for (int sub = 0; sub < 4; sub++)
      #pragma unroll
      for (int r = 0; r < 4; r++) O[sub][r] *= al[r];
    // ---- P: C-layout -> A-layout via LDS ----
    #pragma unroll
    for (int sub = 0; sub < 4; sub++)
      #pragma unroll
      for (int r = 0; r < 4; r++)
        Pw[(quad*4 + r)*68 + sub*16 + i16] = sA[sub][r];
    __syncthreads();
    #pragma unroll
    for (int ks = 0; ks < 2; ks++){
      float p8[8];
      *(float4*)&p8[0] = *(const float4*)(Pw + i16*68 + quad*8 + ks*32);
      *(float4*)&p8[4] = *(const float4*)(Pw + i16*68 + quad*8 + ks*32 + 4);
      ushort_t phb[8], plb[8];
      #pragma unroll
      for (int j = 0; j < 8; j++){
        ushort_t hi = f2bf(p8[j]);
        phb[j] = hi; plb[j] = f2bf(p8[j] - bf2f(hi));
      }
      bf16x8 ph = *(const bf16x8*)phb;
      bf16x8 pl = *(const bf16x8*)plb;
      #pragma unroll
      for (int sub = 0; sub < 4; sub++){
        int off = (sub*16 + i16)*64 + quad*8 + ks*32;
        bf16x8 vfh = *(const bf16x8*)(Vs0 + off);
        bf16x8 vfl = *(const bf16x8*)(Vs1 + off);
        O[sub] = MFMA16(ph, vfh, O[sub]);
        O[sub] = MFMA16(pl, vfh, O[sub]);
        O[sub] = MFMA16(ph, vfl, O[sub]);
      }
    }
    __syncthreads();
  }
  // ---- epilogue: ctx split-bf16 ----
  #pragma unroll
  for (int sub = 0; sub < 4; sub++)
    #pragma unroll
    for (int r = 0; r < 4; r++){
      float val = O[sub][r] / ld_[r];
      size_t t = (size_t)b*S_ + qt*64 + w*16 + quad*4 + r;
      size_t idx = t*D_ + h*64 + sub*16 + i16;
      ushort_t hi = f2bf(val);
      ctxh[idx] = hi;
      ctxl[idx] = f2bf(val - bf2f(hi));
    }
}

// ---------------- RMSNorm2 + task_emb -> xf (f32) + xf_bf ----------------
__global__ __launch_bounds__(256) void k_rms2(const float* __restrict__ x1, const float* __restrict__ w,
    const float* __restrict__ temb, const int* __restrict__ task_id,
    float* __restrict__ xf, ushort_t* __restrict__ xf_bf){
  int t = blockIdx.x; int tid = threadIdx.x;
  const float* xr = x1 + (size_t)t * D_;
  __shared__ float red[256];
  float s = 0.f;
  #pragma unroll
  for (int i = 0; i < 4; i++){ float v = xr[tid + 256*i]; s += v*v; }
  red[tid] = s; __syncthreads();
  for (int o = 128; o > 0; o >>= 1){ if (tid < o) red[tid] += red[tid+o]; __syncthreads(); }
  float rs = rsqrtf(red[0] * (1.f/D_) + 1e-6f);
  int tk = task_id[t];
  #pragma unroll
  for (int i = 0; i < 4; i++){
    int d = tid + 256*i;
    float v = xr[d] * rs * w[d] + temb[(size_t)tk*D_ + d];
    xf[(size_t)t*D_ + d] = v;
    xf_bf[(size_t)t*D_ + d] = f2bf(v);
  }
}

// ---------------- routing ----------------
__global__ __launch_bounds__(64) void k_gate(const float* __restrict__ xf, const float* __restrict__ gW,
    const float* __restrict__ gA, const float* __restrict__ gB,
    int* __restrict__ top_e, float* __restrict__ top_w, int* __restrict__ cnt){
  int t = blockIdx.x; int l = threadIdx.x;
  const float* xr = xf + (size_t)t * D_;
  float aw[8] = {0,0,0,0,0,0,0,0};
  float aa[16] = {0,0,0,0,0,0,0,0,0,0,0,0,0,0,0,0};
  for (int u = 0; u < 16; u++){
    int d = l + u*64;
    float xv = xr[d];
    const float* gwr = gW + (size_t)d*8;
    #pragma unroll
    for (int e = 0; e < 8; e++) aw[e] += xv * gwr[e];
    const float* gar = gA + (size_t)d*16;
    #pragma unroll
    for (int r = 0; r < 16; r++) aa[r] += xv * gar[r];
  }
  #pragma unroll
  for (int e = 0; e < 8; e++){ float v = aw[e]; for (int msk=32; msk; msk>>=1) v += __shfl_xor(v, msk); aw[e] = v; }
  #pragma unroll
  for (int r = 0; r < 16; r++){ float v = aa[r]; for (int msk=32; msk; msk>>=1) v += __shfl_xor(v, msk); aa[r] = v; }
  if (l == 0){
    float lg[8];
    #pragma unroll
    for (int e = 0; e < 8; e++){
      float acc = 0.f;
      #pragma unroll
      for (int r = 0; r < 16; r++) acc += aa[r] * gB[r*8 + e];
      lg[e] = aw[e] + 2.0f * acc;
    }
    int e1 = 0; float v1 = lg[0];
    for (int e = 1; e < 8; e++) if (lg[e] > v1){ v1 = lg[e]; e1 = e; }
    int es = -1; float v2 = -3e38f;
    for (int e = 0; e < 8; e++) if (e != e1 && lg[e] > v2){ v2 = lg[e]; es = e; }
    float z = expf(v2 - v1);
    top_e[2*t] = e1; top_e[2*t+1] = es;
    top_w[2*t] = 1.f/(1.f + z); top_w[2*t+1] = z/(1.f + z);
    atomicAdd(&cnt[e1], 1); atomicAdd(&cnt[es], 1);
  }
}

__global__ void k_scan(const int* cnt, int* offs, int* cursor){
  if (threadIdx.x == 0){
    int a = 0;
    for (int e = 0; e < 8; e++){ offs[e] = a; cursor[e] = a; a += cnt[e]; }
  }
}

__global__ __launch_bounds__(256) void k_build(const int* __restrict__ top_e, const float* __restrict__ top_w,
    int* cursor, int* __restrict__ rowmap, float* __restrict__ roww, int* __restrict__ tok2row){
  int t = blockIdx.x*256 + threadIdx.x;
  #pragma unroll
  for (int s = 0; s < 2; s++){
    int e = top_e[2*t + s];
    int pos = atomicAdd(&cursor[e], 1);
    rowmap[pos] = t; roww[pos] = top_w[2*t + s]; tok2row[2*t + s] = pos;
  }
}

// ---------------- MoE GEMM1 ----------------
__global__ __launch_bounds__(256) void k_moe1(const ushort_t* __restrict__ xf_bf, const ushort_t* __restrict__ W1T,
    const float* __restrict__ b1, const int* __restrict__ rowmap, const int* __restrict__ cnt,
    const int* __restrict__ offs, const ushort_t* __restrict__ zp, ushort_t* __restrict__ h1){
  int e = blockIdx.z;
  int Ne = cnt[e];
  int y0 = blockIdx.y * 128;
  if (y0 >= Ne) return;
  int n0 = blockIdx.x * 128;
  int off = offs[e];
  __shared__ ushort_t As[128*64];
  __shared__ ushort_t Bs[128*64];
  int tid = threadIdx.x, l = tid & 63, w = tid >> 6;
  int wr = w >> 1, wc = w & 1;
  int lr = l >> 3, lc = (l & 7) * 8;
  const ushort_t* BT = W1T + (size_t)e * (4096*1024);
  const ushort_t* aptr[4]; int avk[4];
  const ushort_t* bptr[4];
  #pragma unroll
  for (int i = 0; i < 4; i++){
    int t = w*4 + i;
    int r = t*8 + lr;
    bool v = (y0 + r) < Ne;
    int tok = v ? rowmap[off + y0 + r] : 0;
    aptr[i] = v ? (xf_bf + (size_t)tok*D_ + lc) : (zp + lc);
    avk[i] = v ? 1 : 0;
    bptr[i] = BT + (size_t)(n0 + r)*D_ + lc;
  }
  f32x4 zz = {0.f,0.f,0.f,0.f};
  f32x4 acc[4][4] = {{zz,zz,zz,zz},{zz,zz,zz,zz},{zz,zz,zz,zz},{zz,zz,zz,zz}};
  for (int kt = 0; kt < D_; kt += 64){
    #pragma unroll
    for (int i = 0; i < 4; i++){
      int t = w*4 + i;
      gl_lds16(aptr[i] + (avk[i] ? kt : 0), (void*)(As + t*512));
      gl_lds16(bptr[i] + kt, (void*)(Bs + t*512));
    }
    __syncthreads();
    #pragma unroll
    for (int q = 0; q < 2; q++){
      bf16x8 af[4], bfr[4];
      #pragma unroll
      for (int i = 0; i < 4; i++)
        af[i] = *(const bf16x8*)(As + (wr*64 + i*16 + (l & 15))*64 + q*32 + (l >> 4)*8);
      #pragma unroll
      for (int j = 0; j < 4; j++)
        bfr[j] = *(const bf16x8*)(Bs + (wc*64 + j*16 + (l & 15))*64 + q*32 + (l >> 4)*8);
      #pragma unroll
      for (int i = 0; i < 4; i++)
        #pragma unroll
        for (int j = 0; j < 4; j++)
          acc[i][j] = MFMA16(af[i], bfr[j], acc[i][j]);
    }
    __syncthreads();
  }
  int row4 = (l >> 4)*4, col = l & 15;
  #pragma unroll
  for (int i = 0; i < 4; i++)
    #pragma unroll
    for (int r = 0; r < 4; r++){
      int ml = wr*64 + i*16 + row4 + r;
      if (y0 + ml < Ne){
        size_t grow = off + y0 + ml;
        #pragma unroll
        for (int j = 0; j < 4; j++){
          int nl = n0 + wc*64 + j*16 + col;
          h1[grow*HID_ + nl] = f2bf(acc[i][j][r] + b1[(size_t)e*HID_ + nl]);
        }
      }
    }
}

// ---------------- MoE GEMM2 (dual B) ----------------
__global__ __launch_bounds__(256) void k_moe2(const ushort_t* __restrict__ h1, const ushort_t* __restrict__ WgT,
    const ushort_t* __restrict__ WvT, const float* __restrict__ bg, const float* __restrict__ bvv,
    const int* __restrict__ cnt, const int* __restrict__ offs, const float* __restrict__ roww,
    const ushort_t* __restrict__ zp, float* __restrict__ contrib){
  int e = blockIdx.z;
  int Ne = cnt[e];
  int y0 = blockIdx.y * 128;
  if (y0 >= Ne) return;
  int n0 = blockIdx.x * 64;
  int off = offs[e];
  __shared__ ushort_t As[128*64];
  __shared__ ushort_t Gs[64*64];
  __shared__ ushort_t Vs[64*64];
  int tid = threadIdx.x, l = tid & 63, w = tid >> 6;
  int lr = l >> 3, lc = (l & 7) * 8;
  const ushort_t* GT = WgT + (size_t)e * (1024*4096);
  const ushort_t* VT = WvT + (size_t)e * (1024*4096);
  const ushort_t* aptr[4]; int avk[4];
  #pragma unroll
  for (int i = 0; i < 4; i++){
    int t = w*4 + i;
    int r = t*8 + lr;
    bool v = (y0 + r) < Ne;
    aptr[i] = v ? (h1 + (size_t)(off + y0 + r)*HID_ + lc) : (zp + lc);
    avk[i] = v ? 1 : 0;
  }
  const ushort_t* gptr[2]; const ushort_t* vptr[2];
  #pragma unroll
  for (int i = 0; i < 2; i++){
    int t2 = w*2 + i;
    int r = t2*8 + lr;
    gptr[i] = GT + (size_t)(n0 + r)*HID_ + lc;
    vptr[i] = VT + (size_t)(n0 + r)*HID_ + lc;
  }
  f32x4 zz = {0.f,0.f,0.f,0.f};
  f32x4 ag[2][4] = {{zz,zz,zz,zz},{zz,zz,zz,zz}};
  f32x4 av[2][4] = {{zz,zz,zz,zz},{zz,zz,zz,zz}};
  for (int kt = 0; kt < HID_; kt += 64){
    #pragma unroll
    for (int i = 0; i < 4; i++){
      int t = w*4 + i;
      gl_lds16(aptr[i] + (avk[i] ? kt : 0), (void*)(As + t*512));
    }
    #pragma unroll
    for (int i = 0; i < 2; i++){
      int t2 = w*2 + i;
      gl_lds16(gptr[i] + kt, (void*)(Gs + t2*512));
      gl_lds16(vptr[i] + kt, (void*)(Vs + t2*512));
    }
    __syncthreads();
    #pragma unroll
    for (int q = 0; q < 2; q++){
      bf16x8 af[2], gf[4], vf[4];
      #pragma unroll
      for (int i = 0; i < 2; i++)
        af[i] = *(const bf16x8*)(As + (w*32 + i*16 + (l & 15))*64 + q*32 + (l >> 4)*8);
      #pragma unroll
      for (int j = 0; j < 4; j++){
        gf[j] = *(const bf16x8*)(Gs + (j*16 + (l & 15))*64 + q*32 + (l >> 4)*8);
        vf[j] = *(const bf16x8*)(Vs + (j*16 + (l & 15))*64 + q*32 + (l >> 4)*8);
      }
      #pragma unroll
      for (int i = 0; i < 2; i++)
        #pragma unroll
        for (int j = 0; j < 4; j++){
          ag[i][j] = MFMA16(af[i], gf[j], ag[i][j]);
          av[i][j] = MFMA16(af[i], vf[j], av[i][j]);
        }
    }
    __syncthreads();
  }
  int row4 = (l >> 4)*4, col = l & 15;
  #pragma unroll
  for (int i = 0; i < 2; i++)
    #pragma unroll
    for (int r = 0; r < 4; r++){
      int ml = w*32 + i*16 + row4 + r;
      if (y0 + ml < Ne){
        size_t grow = off + y0 + ml;
        float wgt = roww[grow];
        #pragma unroll
        for (int j = 0; j < 4; j++){
          int nl = n0 + j*16 + col;
          float g = ag[i][j][r] + bg[(size_t)e*D_ + nl];
          float v = av[i][j][r] + bvv[(size_t)e*D_ + nl];
          float sg = 1.f/(1.f + expf(-g));
          contrib[grow*D_ + nl] = wgt * g * sg * v;
        }
      }
    }
}

// ---------------- final ----------------
__global__ __launch_bounds__(256) void k_final(const float* __restrict__ x1, const float* __restrict__ contrib,
    const int* __restrict__ tok2row, float* __restrict__ out){
  int t = blockIdx.x; int i = threadIdx.x;
  int r0 = tok2row[2*t], r1 = tok2row[2*t+1];
  float4 a = *(const float4*)&x1[(size_t)t*D_ + i*4];
  float4 c0 = *(const float4*)&contrib[(size_t)r0*D_ + i*4];
  float4 c1 = *(const float4*)&contrib[(size_t)r1*D_ + i*4];
  a.x += c0.x + c1.x; a.y += c0.y + c1.y; a.z += c0.z + c1.z; a.w += c0.w + c1.w;
  *(float4*)&out[(size_t)t*D_ + i*4] = a;
}

extern "C" void kernel_launch(void* const* d_in, const int* in_sizes, int n_in,
                              void* d_out, int out_size, void* d_ws, size_t ws_size,
                              hipStream_t stream){
  (void)in_sizes; (void)n_in; (void)out_size; (void)ws_size;
  const float* x    = (const float*)d_in[0];
  const float* fc   = (const float*)d_in[1];
  const float* fs   = (const float*)d_in[2];
  const int*   tsk  = (const int*)d_in[3];
  const float* n1w  = (const float*)d_in[4];
  const float* n2w  = (const float*)d_in[5];
  const float* WqT  = (const float*)d_in[6];
  const float* WkT  = (const float*)d_in[7];
  const float* WvTp = (const float*)d_in[8];
  const float* WoT  = (const float*)d_in[9];
  const float* qA   = (const float*)d_in[10]; const float* qB = (const float*)d_in[11];
  const float* kA   = (const float*)d_in[12]; const float* kB = (const float*)d_in[13];
  const float* vA   = (const float*)d_in[14]; const float* vB = (const float*)d_in[15];
  const float* gW   = (const float*)d_in[16]; const float* gA = (const float*)d_in[17];
  const float* gB   = (const float*)d_in[18];
  const float* temb = (const float*)d_in[19];
  const float* eW1  = (const float*)d_in[20]; const float* eb1 = (const float*)d_in[21];
  const float* eWg  = (const float*)d_in[22]; const float* ebg = (const float*)d_in[23];
  const float* eWv  = (const float*)d_in[24]; const float* ebv = (const float*)d_in[25];
  float* out = (float*)d_out;

  char* wsc = (char*)d_ws;
  size_t o = 0;
  auto alloc = [&](size_t bytes)->void*{ void* p = wsc + o; o = (o + bytes + 255) & ~(size_t)255; return p; };
  // ---- persistent ----
  ushort_t* zp     = (ushort_t*)alloc(1024);
  int*   cnt    = (int*)alloc(64);
  int*   offs   = (int*)alloc(64);
  int*   cursor = (int*)alloc(64);
  int*   top_e  = (int*)alloc((size_t)T_*2*4);
  float* top_w  = (float*)alloc((size_t)T_*2*4);
  int*   rowmap = (int*)alloc((size_t)2*T_*4);
  float* roww   = (float*)alloc((size_t)2*T_*4);
  int*   tok2row= (int*)alloc((size_t)2*T_*4);
  float* x1     = (float*)alloc((size_t)T_*D_*4);
  ushort_t* xf_bf  = (ushort_t*)alloc((size_t)T_*D_*2);
  ushort_t* W1T    = (ushort_t*)alloc((size_t)E_*D_*HID_*2);
  ushort_t* WgTb   = (ushort_t*)alloc((size_t)E_*HID_*D_*2);
  ushort_t* WvTb   = (ushort_t*)alloc((size_t)E_*HID_*D_*2);
  ushort_t* WeTh   = (ushort_t*)alloc((size_t)QKVN*D_*2);
  ushort_t* WeTl   = (ushort_t*)alloc((size_t)QKVN*D_*2);
  ushort_t* WoTh   = (ushort_t*)alloc((size_t)D_*D_*2);
  ushort_t* WoTl   = (ushort_t*)alloc((size_t)D_*D_*2);
  // ---- pooled phase-1 buffers (overlaid by h1+contrib in phase 2) ----
  size_t poolbase = o;
  ushort_t* h_hi = (ushort_t*)alloc((size_t)T_*D_*2);
  ushort_t* h_lo = (ushort_t*)alloc((size_t)T_*D_*2);
  float* Weff = (float*)alloc((size_t)D_*QKVN*4);
  ushort_t* Qsh = (ushort_t*)alloc((size_t)T_*D_*2);
  ushort_t* Qsl = (ushort_t*)alloc((size_t)T_*D_*2);
  ushort_t* Ksh = (ushort_t*)alloc((size_t)T_*KV_*2);
  ushort_t* Ksl = (ushort_t*)alloc((size_t)T_*KV_*2);
  ushort_t* Vth = (ushort_t*)alloc((size_t)T_*KV_*2);
  ushort_t* Vtl = (ushort_t*)alloc((size_t)T_*KV_*2);
  float* QKV  = (float*)alloc((size_t)T_*QKVN*4);
  float* xf   = (float*)alloc((size_t)T_*D_*4);
  // ctx overlays QKV (QKV dead after k_rope; ctx written by k_attn after)
  ushort_t* ctxh = (ushort_t*)QKV;
  ushort_t* ctxl = (ushort_t*)QKV + (size_t)T_*D_;
  // phase-2 overlay: h1 at poolbase (33.6 MB), contrib after (16.8 MB); xf at +43.9 MB
  // is only read by k_gate which precedes k_moe2's contrib writes.
  ushort_t* h1   = (ushort_t*)(wsc + poolbase);
  float* contrib = (float*)(wsc + poolbase + (size_t)2*T_*HID_*2);

  k_init<<<1, 256, 0, stream>>>(cnt, zp);
  k_rms1<<<T_, 256, 0, stream>>>(x, n1w, h_hi, h_lo);
  k_weff<<<D_, 256, 0, stream>>>(WqT, WkT, WvTp, qA, qB, kA, kB, vA, vB, Weff);
  k_trans<1><<<dim3(QKVN/64, D_/64, 1), 256, 0, stream>>>(Weff, WeTh, WeTl, D_, QKVN, 0, 0);
  k_trans<1><<<dim3(D_/64, D_/64, 1), 256, 0, stream>>>(WoT, WoTh, WoTl, D_, D_, 0, 0);
  k_trans<0><<<dim3(HID_/64, D_/64, E_), 256, 0, stream>>>(eW1, W1T, nullptr, D_, HID_, (size_t)D_*HID_, (size_t)HID_*D_);
  k_trans<0><<<dim3(D_/64, HID_/64, E_), 256, 0, stream>>>(eWg, WgTb, nullptr, HID_, D_, (size_t)HID_*D_, (size_t)D_*HID_);
  k_trans<0><<<dim3(D_/64, HID_/64, E_), 256, 0, stream>>>(eWv, WvTb, nullptr, HID_, D_, (size_t)HID_*D_, (size_t)D_*HID_);
  k_gemm3<0><<<dim3(QKVN/128, T_/64), 256, 0, stream>>>(h_hi, h_lo, WeTh, WeTl, nullptr, QKV, T_, QKVN, D_);
  k_rope<<<T_, 256, 0, stream>>>(QKV, fc, fs, Qsh, Qsl, Ksh, Ksl, Vth, Vtl);
  k_attn<<<dim3(16, 32), 256, 0, stream>>>(Qsh, Qsl, Ksh, Ksl, Vth, Vtl, ctxh, ctxl);
  k_gemm3<1><<<dim3(D_/128, T_/64), 256, 0, stream>>>(ctxh, ctxl, WoTh, WoTl, x, x1, T_, D_, D_);
  k_rms2<<<T_, 256, 0, stream>>>(x1, n2w, temb, tsk, xf, xf_bf);
  k_gate<<<T_, 64, 0, stream>>>(xf, gW, gA, gB, top_e, top_w, cnt);
  k_scan<<<1, 64, 0, stream>>>(cnt, offs, cursor);
  k_build<<<T_/256, 256, 0, stream>>>(top_e, top_w, cursor, rowmap, roww, tok2row);
  k_moe1<<<dim3(HID_/128, 16, E_), 256, 0, stream>>>(xf_bf, W1T, eb1, rowmap, cnt, offs, zp, h1);
  k_moe2<<<dim3(D_/64, 16, E_), 256, 0, stream>>>(h1, WgTb, WvTb, ebg, ebv, cnt, offs, roww, zp, contrib);
  k_final<<<T_, 256, 0, stream>>>(x1, contrib, tok2row, out);
}